// Round 9
// baseline (192.884 us; speedup 1.0000x reference)
//
#include <hip/hip_runtime.h>
#include <hip/hip_bf16.h>
#include <math.h>
#include <stdint.h>

#define NB 4
#define NS 2048
#define ND 512
#define NH 8
#define DEP 64
#define KVQ (NS / 4)  // kv quarter: grid.z (2) x in-block zh (2)

typedef __attribute__((ext_vector_type(8))) short bf16x8;
typedef __attribute__((ext_vector_type(4))) short bf16x4;
typedef __attribute__((ext_vector_type(4))) float f32x4;
typedef __attribute__((ext_vector_type(16))) float f32x16;

#define QSCALE 0.18033688011112042f  // DEPTH^-0.5 * log2(e): softmax in exp2

__device__ __forceinline__ short f2b(float f) {
  unsigned u = __float_as_uint(f);
  u += 0x7FFF + ((u >> 16) & 1);  // RNE
  return (short)(u >> 16);
}
__device__ __forceinline__ float b2f(short s) {
  return __uint_as_float(((unsigned)(unsigned short)s) << 16);
}
__device__ __forceinline__ unsigned pk2(float a, float b) {
  union { __hip_bfloat162 h; unsigned u; } c;
  c.h = __float22bfloat162_rn(float2{a, b});
  return c.u;
}
// async 16B global->LDS DMA; LDS dest is wave-uniform base + lane*16
__device__ __forceinline__ void dma16(const void* g, void* l) {
  __builtin_amdgcn_global_load_lds(
      (const __attribute__((address_space(1))) void*)g,
      (__attribute__((address_space(3))) void*)l, 16, 0, 0);
}

// ---------------------------------------------------------------------------
// prep: one launch does BOTH input casts and all 4 weight transposes.
// grid (4096, 3): y=0 cast x, y=1 cast y, y=2 (x<256) transpose W0..W3.
// ---------------------------------------------------------------------------
__global__ __launch_bounds__(256) void prep(
    const float* __restrict__ x, const float* __restrict__ y,
    const float* __restrict__ W0, const float* __restrict__ W1,
    const float* __restrict__ W2, const float* __restrict__ W3,
    short* __restrict__ xb, short* __restrict__ yb, short* __restrict__ T0,
    short* __restrict__ T1, short* __restrict__ T2, short* __restrict__ T3) {
  const int t = threadIdx.x;
  if (blockIdx.y < 2) {
    const float* src = blockIdx.y ? y : x;
    short* dst = blockIdx.y ? yb : xb;
    size_t i = ((size_t)blockIdx.x * 256 + t) * 4;
    float4 v = *(const float4*)(src + i);
    bf16x4 o;
    o[0] = f2b(v.x); o[1] = f2b(v.y); o[2] = f2b(v.z); o[3] = f2b(v.w);
    *(bf16x4*)(dst + i) = o;
    return;
  }
  const int bx = blockIdx.x;
  if (bx >= 256) return;
  const int wj = bx >> 6, rem = bx & 63;
  const float* W = wj == 0 ? W0 : wj == 1 ? W1 : wj == 2 ? W2 : W3;
  short* T = wj == 0 ? T0 : wj == 1 ? T1 : wj == 2 ? T2 : T3;
  __shared__ float tile[64][65];
  const int k0 = (rem >> 3) * 64, n0 = (rem & 7) * 64;
#pragma unroll
  for (int i = 0; i < 4; ++i) {
    int r = (t >> 4) + i * 16;
    int c = (t & 15) * 4;
    float4 v = *(const float4*)&W[(size_t)(k0 + r) * ND + n0 + c];
    tile[r][c] = v.x; tile[r][c + 1] = v.y;
    tile[r][c + 2] = v.z; tile[r][c + 3] = v.w;
  }
  __syncthreads();
#pragma unroll
  for (int i = 0; i < 4; ++i) {
    int n = (t >> 4) + i * 16;
    int kc = (t & 15) * 4;
    bf16x4 o;
#pragma unroll
    for (int j = 0; j < 4; ++j) o[j] = f2b(tile[kc + j][n]);
    *(bf16x4*)&T[(size_t)(n0 + n) * ND + k0 + kc] = o;
  }
}

// ---------------------------------------------------------------------------
// QKV GEMM: 128x128 tile, 4 waves each 64x64 (acc 4x4), BK=64, single-buffer
// DMA staging (m97 2-barrier), XOR-swizzled LDS (pitch 64, chunk ^= row&7).
// mode 1: bf16 row-major out; 2: bf16 V^T out via LDS-transposed coalesced
// epilogue.
// ---------------------------------------------------------------------------
__device__ __forceinline__ void gemm128(const short* __restrict__ A,
                                        const short* __restrict__ Bt,
                                        short* __restrict__ Cout, int mode,
                                        float alpha) {
  __shared__ short As[128 * 64];
  __shared__ short Bs[128 * 64];
  __shared__ short Tb[64 * 128];  // mode-2 transpose staging [c][r], 16 KB
  const int t = threadIdx.x;
  const int wave = t >> 6, lane = t & 63;
  const int m = lane & 15, quad = lane >> 4;
  const int m0 = blockIdx.y * 128, n0 = blockIdx.x * 128;
  const int mh = (wave >> 1) * 64, nh = (wave & 1) * 64;
  const int r8 = lane >> 3;        // 0..7: row within wave's staging band
  const int c8 = (lane & 7) ^ r8;  // swizzled global chunk for this lane
  const int mx7 = m & 7;           // fragment-read swizzle key
  f32x4 acc[4][4];
#pragma unroll
  for (int i = 0; i < 4; ++i)
#pragma unroll
    for (int j = 0; j < 4; ++j) acc[i][j] = (f32x4){0.f, 0.f, 0.f, 0.f};

  for (int k0 = 0; k0 < ND; k0 += 64) {
    __syncthreads();  // prior iteration's fragment readers done
#pragma unroll
    for (int i = 0; i < 4; ++i) {
      int row = i * 32 + wave * 8 + r8;
      dma16(A + (size_t)(m0 + row) * ND + k0 + c8 * 8,
            As + (i * 256 + wave * 64) * 8);
      dma16(Bt + (size_t)(n0 + row) * ND + k0 + c8 * 8,
            Bs + (i * 256 + wave * 64) * 8);
    }
    __syncthreads();  // drains vmcnt: all DMA visible
    bf16x8 af[4][2], bf[4][2];
#pragma unroll
    for (int mt = 0; mt < 4; ++mt)
#pragma unroll
      for (int kc = 0; kc < 2; ++kc)
        af[mt][kc] = *(const bf16x8*)(As + (mh + mt * 16 + m) * 64 +
                                      ((kc * 4 + quad) ^ mx7) * 8);
#pragma unroll
    for (int nt = 0; nt < 4; ++nt)
#pragma unroll
      for (int kc = 0; kc < 2; ++kc)
        bf[nt][kc] = *(const bf16x8*)(Bs + (nh + nt * 16 + m) * 64 +
                                      ((kc * 4 + quad) ^ mx7) * 8);
#pragma unroll
    for (int mt = 0; mt < 4; ++mt)
#pragma unroll
      for (int nt = 0; nt < 4; ++nt)
#pragma unroll
        for (int kc = 0; kc < 2; ++kc)
          acc[mt][nt] = __builtin_amdgcn_mfma_f32_16x16x32_bf16(
              af[mt][kc], bf[nt][kc], acc[mt][nt], 0, 0, 0);
  }
  if (mode == 2) {
    // V^T epilogue: two 64-col passes through Tb[c][r], then each thread
    // writes 64 B of s-contiguous V^T (256 B contiguous per channel row).
    const int h0 = n0 >> 6;                        // n0 is 128-aligned
    const int b_ = m0 >> 11, s0g = m0 & (NS - 1);  // 128-row tile: one b
#pragma unroll
    for (int p = 0; p < 2; ++p) {
      __syncthreads();  // Tb free (p0: main loop done; p1: p0 readers done)
      if ((wave & 1) == p) {
        // wave's cols nh + nt*16 + m, nh == p*64 -> local c = nt*16 + m
#pragma unroll
        for (int mt = 0; mt < 4; ++mt)
#pragma unroll
          for (int nt = 0; nt < 4; ++nt)
#pragma unroll
            for (int r = 0; r < 4; ++r)
              Tb[(nt * 16 + m) * 128 + mh + mt * 16 + quad * 4 + r] =
                  f2b(acc[mt][nt][r] * alpha);
      }
      __syncthreads();
      {
        int c = t >> 2, sc = (t & 3) * 32;  // c: 0..63, sc: 0/32/64/96
        int gcol = p * 64 + c;
        int h_ = h0 + (gcol >> 6), d_ = gcol & (DEP - 1);
        short* dst =
            Cout + (size_t)((b_ * NH + h_) * DEP + d_) * NS + s0g + sc;
        const short* src = Tb + c * 128 + sc;
#pragma unroll
        for (int i = 0; i < 4; ++i)
          *(bf16x8*)(dst + i * 8) = *(const bf16x8*)(src + i * 8);
      }
    }
  } else {
#pragma unroll
    for (int mt = 0; mt < 4; ++mt)
#pragma unroll
      for (int nt = 0; nt < 4; ++nt)
#pragma unroll
        for (int r = 0; r < 4; ++r) {
          int row = m0 + mh + mt * 16 + quad * 4 + r;
          int col = n0 + nh + nt * 16 + m;
          Cout[(size_t)row * ND + col] = f2b(acc[mt][nt][r] * alpha);
        }
  }
}

__global__ __launch_bounds__(256) void qkv_gemm(
    const short* __restrict__ xb, const short* __restrict__ yb,
    const short* __restrict__ Wqt, const short* __restrict__ Wkt,
    const short* __restrict__ Wvt, short* __restrict__ Qb,
    short* __restrict__ Kb, short* __restrict__ Vtb) {
  if (blockIdx.z == 0)
    gemm128(xb, Wqt, Qb, 1, QSCALE);  // scale + log2e folded into Q
  else if (blockIdx.z == 1)
    gemm128(yb, Wkt, Kb, 1, 1.0f);
  else
    gemm128(yb, Wvt, Vtb, 2, 1.0f);
}

// ---------------------------------------------------------------------------
// Output GEMM: 128x64 tile, BK=64, double-buffered DMA, swizzled LDS,
// fp32 row-major out.  Grid 512 = 2 blocks/CU.
// ---------------------------------------------------------------------------
__global__ __launch_bounds__(256) void out_gemm(const short* __restrict__ A,
                                                const short* __restrict__ Bt,
                                                float* __restrict__ Cout) {
  __shared__ short As[2][128 * 64];
  __shared__ short Bs[2][64 * 64];
  const int t = threadIdx.x;
  const int wave = t >> 6, lane = t & 63;
  const int m = lane & 15, quad = lane >> 4;
  const int m0 = blockIdx.y * 128, n0 = blockIdx.x * 64;
  const int mh = (wave >> 1) * 64, nh = (wave & 1) * 32;
  const int r8 = lane >> 3;
  const int c8 = (lane & 7) ^ r8;
  const int mx7 = m & 7;
  f32x4 acc[4][2];
#pragma unroll
  for (int i = 0; i < 4; ++i)
#pragma unroll
    for (int j = 0; j < 2; ++j) acc[i][j] = (f32x4){0.f, 0.f, 0.f, 0.f};

#pragma unroll
  for (int i = 0; i < 4; ++i)
    dma16(A + (size_t)(m0 + i * 32 + wave * 8 + r8) * ND + c8 * 8,
          As[0] + (i * 256 + wave * 64) * 8);
#pragma unroll
  for (int i = 0; i < 2; ++i)
    dma16(Bt + (size_t)(n0 + i * 32 + wave * 8 + r8) * ND + c8 * 8,
          Bs[0] + (i * 256 + wave * 64) * 8);

  int buf = 0;
  for (int k0 = 0; k0 < ND; k0 += 64, buf ^= 1) {
    __syncthreads();
    if (k0 + 64 < ND) {
#pragma unroll
      for (int i = 0; i < 4; ++i)
        dma16(A + (size_t)(m0 + i * 32 + wave * 8 + r8) * ND + k0 + 64 + c8 * 8,
              As[buf ^ 1] + (i * 256 + wave * 64) * 8);
#pragma unroll
      for (int i = 0; i < 2; ++i)
        dma16(Bt + (size_t)(n0 + i * 32 + wave * 8 + r8) * ND + k0 + 64 +
                  c8 * 8,
              Bs[buf ^ 1] + (i * 256 + wave * 64) * 8);
    }
    bf16x8 af[4][2], bf[2][2];
#pragma unroll
    for (int mt = 0; mt < 4; ++mt)
#pragma unroll
      for (int kc = 0; kc < 2; ++kc)
        af[mt][kc] = *(const bf16x8*)(As[buf] + (mh + mt * 16 + m) * 64 +
                                      ((kc * 4 + quad) ^ mx7) * 8);
#pragma unroll
    for (int nt = 0; nt < 2; ++nt)
#pragma unroll
      for (int kc = 0; kc < 2; ++kc)
        bf[nt][kc] = *(const bf16x8*)(Bs[buf] + (nh + nt * 16 + m) * 64 +
                                      ((kc * 4 + quad) ^ mx7) * 8);
#pragma unroll
    for (int mt = 0; mt < 4; ++mt)
#pragma unroll
      for (int nt = 0; nt < 2; ++nt)
#pragma unroll
        for (int kc = 0; kc < 2; ++kc)
          acc[mt][nt] = __builtin_amdgcn_mfma_f32_16x16x32_bf16(
              af[mt][kc], bf[nt][kc], acc[mt][nt], 0, 0, 0);
  }
#pragma unroll
  for (int mt = 0; mt < 4; ++mt)
#pragma unroll
    for (int nt = 0; nt < 2; ++nt)
#pragma unroll
      for (int r = 0; r < 4; ++r) {
        int row = m0 + mh + mt * 16 + quad * 4 + r;
        int col = n0 + nh + nt * 16 + m;
        Cout[(size_t)row * ND + col] = acc[mt][nt][r];
      }
}

// ---------------------------------------------------------------------------
// Flash attention, S^T formulation, 32x32x16 MFMA, in-register softmax.
// kv-split x4 total: grid.z (2 blocks) x in-block zh (2 wave-groups), each
// wave-group covers a 512-kv quarter (8 tiles).  Grid (16,32,2) = 1024
// blocks = 4 blocks/CU = 32 waves/CU -- r8's occupancy was GRID-limited at
// 2 blocks/CU (512 blocks); LDS/VGPR already allowed 4.
// Single-buffered K/V (m97 2-barrier), 32.5 KB LDS, VGPR<=64.
// Max-free softmax: partials combine exactly.  In-block zh pair combines
// via LDS (fp32); cross-block z partials go to global as UNNORMALIZED bf16
// O^p [z][bh][s][d] + fp32 l^p [z][bh][s]; tiny elementwise combine kernel
// computes O = (O0+O1)/(l0+l1).
// ---------------------------------------------------------------------------
__global__ __launch_bounds__(512, 4) void attn_mfma(
    const short* __restrict__ Qb, const short* __restrict__ Kb,
    const short* __restrict__ Vtb, short* __restrict__ Op,
    float* __restrict__ lp) {
  __shared__ short KVs[2][2][64 * 64];  // [K=0/V=1][zh][kv/d tile], 32 KB
  __shared__ float lxs[128];            // cross-zh l exchange
  const int t = threadIdx.x;
  const int wave = t >> 6, lane = t & 63;
  const int zh = wave >> 2, wl = wave & 3;  // kv-subquarter, q-subtile
  const int l31 = lane & 31, hi = lane >> 5;
  const int sw = lane & 7;  // fragment-read swizzle key (row&7 == lane&7)
  const int bh = blockIdx.y, b = bh >> 3, h = bh & 7;
  const int q0 = blockIdx.x * 128 + wl * 32;
  const int kvb = (blockIdx.z * 2 + zh) * KVQ;
  const size_t rowb = (size_t)b * NS;
  const short* Vtbase = Vtb + (size_t)(bh * DEP) * NS;
  const int r8 = lane >> 3;
  const int c8 = (lane & 7) ^ r8;
  short* Ksb = &KVs[0][zh][0];
  short* Vsb = &KVs[1][zh][0];

  // Q fragments (B-operand): col=q=l31, k(d) = dc*16 + hi*8 + j
  bf16x8 qf[4];
#pragma unroll
  for (int dc = 0; dc < 4; ++dc)
    qf[dc] = *(const bf16x8*)(Qb + (rowb + q0 + l31) * ND + h * DEP + dc * 16 +
                              hi * 8);

  // loop-invariant zero C-operand: avoids 32 v_mov per iteration (St init)
  f32x16 kzero;
#pragma unroll
  for (int i = 0; i < 16; ++i) kzero[i] = 0.f;

  float l_ = 0.0f;
  f32x16 Ot[2];
#pragma unroll
  for (int dt = 0; dt < 2; ++dt)
#pragma unroll
    for (int i = 0; i < 16; ++i) Ot[dt][i] = 0.f;

  for (int kv0 = 0; kv0 < KVQ; kv0 += 64) {
    __syncthreads();  // prior iteration's fragment readers done
#pragma unroll
    for (int i = 0; i < 2; ++i) {
      int row = i * 32 + wl * 8 + r8;
      dma16(Kb + (rowb + kvb + kv0 + row) * ND + h * DEP + c8 * 8,
            Ksb + (i * 256 + wl * 64) * 8);
      dma16(Vtbase + (size_t)row * NS + kvb + kv0 + c8 * 8,
            Vsb + (i * 256 + wl * 64) * 8);
    }
    __syncthreads();  // drains vmcnt: K/V tiles visible

    // QK^T: St[kt] = S^T tile (kv = kt*32+row, q = col = l31)
    f32x16 St[2];
#pragma unroll
    for (int kt = 0; kt < 2; ++kt) {
      bf16x8 kf0 = *(const bf16x8*)(Ksb + (kt * 32 + l31) * 64 +
                                    (hi ^ sw) * 8);
      St[kt] = __builtin_amdgcn_mfma_f32_32x32x16_bf16(kf0, qf[0], kzero,
                                                       0, 0, 0);
#pragma unroll
      for (int dc = 1; dc < 4; ++dc) {
        bf16x8 kf = *(const bf16x8*)(Ksb + (kt * 32 + l31) * 64 +
                                     ((dc * 2 + hi) ^ sw) * 8);
        St[kt] = __builtin_amdgcn_mfma_f32_32x32x16_bf16(kf, qf[dc], St[kt],
                                                         0, 0, 0);
      }
    }

    // softmax (max-free, exp2) + in-register P^T -> B-fragment assembly.
    // St reg r (tile kt): kv = kt*32 + (r&3) + 8*(r>>2) + 4*hi.
    // B-frag slice s needs: elem j = P[kv0 + s*16 + hi*8 + j][q].
    bf16x8 pf[4];
    float rs = 0.f;
#pragma unroll
    for (int s = 0; s < 4; ++s) {
      const int kt = s >> 1, base = (s & 1) * 8;
      float E[8];
#pragma unroll
      for (int j = 0; j < 8; ++j) {
        E[j] = __builtin_amdgcn_exp2f(St[kt][base + j]);
      }
      rs += ((E[0] + E[1]) + (E[2] + E[3])) + ((E[4] + E[5]) + (E[6] + E[7]));
      unsigned A0 = pk2(E[0], E[1]), A1 = pk2(E[2], E[3]);
      unsigned A2 = pk2(E[4], E[5]), A3 = pk2(E[6], E[7]);
      // swap: out0 = [a.lo | b.lo], out1 = [a.hi | b.hi]
      auto r02 =
          __builtin_amdgcn_permlane32_swap((int)A0, (int)A2, false, false);
      auto r13 =
          __builtin_amdgcn_permlane32_swap((int)A1, (int)A3, false, false);
      union { bf16x8 v; int u[4]; } pu;
      pu.u[0] = r02[0]; pu.u[1] = r13[0]; pu.u[2] = r02[1]; pu.u[3] = r13[1];
      pf[s] = pu.v;
    }
    l_ += rs;

    // PV: Ot^T[dt] += V^T[d, kv-slice] * P^T[kv-slice, q]
#pragma unroll
    for (int dt = 0; dt < 2; ++dt)
#pragma unroll
      for (int s = 0; s < 4; ++s) {
        bf16x8 vf = *(const bf16x8*)(Vsb + (dt * 32 + l31) * 64 +
                                     ((s * 2 + hi) ^ sw) * 8);
        Ot[dt] = __builtin_amdgcn_mfma_f32_32x32x16_bf16(vf, pf[s], Ot[dt],
                                                         0, 0, 0);
      }
  }

  // per-wave denominator partial: lane l and l^32 hold complementary kv sets
  l_ += __shfl_xor(l_, 32, 64);

  // in-block zh combine in LDS (aliased over dead K/V staging buffers).
  __syncthreads();  // all K/V fragment reads of the last tile complete
  float* Ox = (float*)KVs;  // [4][64][32] fp32 = 32 KB (spans KVs exactly)
  if (zh == 1) {
#pragma unroll
    for (int dt = 0; dt < 2; ++dt)
#pragma unroll
      for (int r = 0; r < 16; ++r) {
        int d = dt * 32 + (r & 3) + 8 * (r >> 2) + 4 * hi;
        Ox[(wl * 64 + d) * 32 + l31] = Ot[dt][r];
      }
    if (lane < 32) lxs[wl * 32 + l31] = l_;
  }
  __syncthreads();
  if (zh == 0) {
    float lsum = l_ + lxs[wl * 32 + l31];
    size_t prow = (size_t)(blockIdx.z * 32 + bh) * NS + q0 + l31;
    if (lane < 32) lp[prow] = lsum;
    short* obase = Op + prow * DEP;
    // unnormalized bf16 partial, Ot reg r (tile dt):
    // d = dt*32 + (r&3) + 8*(r>>2) + 4*hi -> 8B stores
#pragma unroll
    for (int dt = 0; dt < 2; ++dt)
#pragma unroll
      for (int g = 0; g < 4; ++g) {
        int d0 = dt * 32 + g * 8 + hi * 4;
        float o[4];
#pragma unroll
        for (int j = 0; j < 4; ++j)
          o[j] = Ot[dt][g * 4 + j] + Ox[(wl * 64 + d0 + j) * 32 + l31];
        uint2 pk;
        pk.x = pk2(o[0], o[1]);
        pk.y = pk2(o[2], o[3]);
        *(uint2*)(obase + d0) = pk;
      }
  }
}

// ---------------------------------------------------------------------------
// combine: O = (O0+O1)/(l0+l1), elementwise, fully coalesced (128 B per
// (bh,s) row).  [z][bh][s][d] bf16 partials -> attnb [b*S+s][h*64+d] bf16.
// grid (32 s-tiles, 32 bh), 256 threads; thread = 16 d of one s.
// ---------------------------------------------------------------------------
__global__ __launch_bounds__(256) void combine(const short* __restrict__ Op,
                                               const float* __restrict__ lp,
                                               short* __restrict__ Ob) {
  const int t = threadIdx.x;
  const int bh = blockIdx.y, b = bh >> 3, h = bh & 7;
  const int s = blockIdx.x * 64 + (t >> 2), dc = (t & 3) * 16;
  const size_t zo = (size_t)32 * NS * DEP;   // Op z-stride (elements)
  const size_t zl = (size_t)32 * NS;         // lp z-stride
  const size_t p0 = ((size_t)bh * NS + s) * DEP + dc;
  bf16x8 a0 = *(const bf16x8*)(Op + p0);
  bf16x8 a1 = *(const bf16x8*)(Op + p0 + 8);
  bf16x8 c0 = *(const bf16x8*)(Op + zo + p0);
  bf16x8 c1 = *(const bf16x8*)(Op + zo + p0 + 8);
  const size_t li = (size_t)bh * NS + s;
  float linv = 1.0f / (lp[li] + lp[zl + li]);
  bf16x8 o0, o1;
#pragma unroll
  for (int j = 0; j < 8; ++j) {
    o0[j] = f2b((b2f(a0[j]) + b2f(c0[j])) * linv);
    o1[j] = f2b((b2f(a1[j]) + b2f(c1[j])) * linv);
  }
  short* dst = Ob + ((size_t)b * NS + s) * ND + h * DEP + dc;
  *(bf16x8*)dst = o0;
  *(bf16x8*)(dst + 8) = o1;
}

// ---------------------------------------------------------------------------
extern "C" void kernel_launch(void* const* d_in, const int* in_sizes, int n_in,
                              void* d_out, int out_size, void* d_ws,
                              size_t ws_size, hipStream_t stream) {
  const float* x = (const float*)d_in[0];
  const float* y = (const float*)d_in[1];
  const float* Wq = (const float*)d_in[2];
  const float* Wk = (const float*)d_in[3];
  const float* Wv = (const float*)d_in[4];
  const float* Wo = (const float*)d_in[5];
  float* out = (float*)d_out;

  const size_t mat = (size_t)NB * NS * ND;  // 4.19M elems = 8.39 MB bf16
  const size_t wsz = (size_t)ND * ND;       // 262K elems = 0.52 MB bf16
  short* xb = (short*)d_ws;
  short* yb = xb + mat;
  short* Wqt = yb + mat;
  short* Wkt = Wqt + wsz;
  short* Wvt = Wkt + wsz;
  short* Wot = Wvt + wsz;
  short* Qb = Wot + wsz;
  short* Kb = Qb + mat;
  short* Vtb = Kb + mat;
  // attn overlays (sizes verified):
  //  Opart bf16 [2][32][2048][64] = 2*mat elems = 16.78 MB = xb+yb EXACTLY
  //  lpart fp32 [2][32][2048] = 131072 f32 = 524288 B = Wqt EXACTLY
  //  (xb, yb, Wqt all dead after qkv_gemm; Qb dead after attn -> attnb)
  short* Opart = xb;
  float* lpart = (float*)Wqt;
  short* attnb = Qb;

  prep<<<dim3(mat / 1024, 3), 256, 0, stream>>>(x, y, Wq, Wk, Wv, Wo, xb, yb,
                                                Wqt, Wkt, Wvt, Wot);
  qkv_gemm<<<dim3(ND / 128, (NB * NS) / 128, 3), 256, 0, stream>>>(
      xb, yb, Wqt, Wkt, Wvt, Qb, Kb, Vtb);
  attn_mfma<<<dim3(NS / 128, NB * NH, 2), 512, 0, stream>>>(Qb, Kb, Vtb,
                                                            Opart, lpart);
  combine<<<dim3(NS / 64, NB * NH), 256, 0, stream>>>(Opart, lpart, attnb);
  out_gemm<<<dim3(ND / 64, (NB * NS) / 128), 256, 0, stream>>>(attnb, Wot,
                                                               out);
}

// Round 10
// 183.262 us; speedup vs baseline: 1.0525x; 1.0525x over previous
//
#include <hip/hip_runtime.h>
#include <hip/hip_bf16.h>
#include <math.h>
#include <stdint.h>

#define NB 4
#define NS 2048
#define ND 512
#define NH 8
#define DEP 64
#define KVHALF (NS / 2)

typedef __attribute__((ext_vector_type(8))) short bf16x8;
typedef __attribute__((ext_vector_type(4))) short bf16x4;
typedef __attribute__((ext_vector_type(4))) float f32x4;
typedef __attribute__((ext_vector_type(16))) float f32x16;

#define QSCALE 0.18033688011112042f  // DEPTH^-0.5 * log2(e): softmax in exp2

__device__ __forceinline__ short f2b(float f) {
  unsigned u = __float_as_uint(f);
  u += 0x7FFF + ((u >> 16) & 1);  // RNE
  return (short)(u >> 16);
}
__device__ __forceinline__ unsigned pk2(float a, float b) {
  union { __hip_bfloat162 h; unsigned u; } c;
  c.h = __float22bfloat162_rn(float2{a, b});
  return c.u;
}
// async 16B global->LDS DMA; LDS dest is wave-uniform base + lane*16
__device__ __forceinline__ void dma16(const void* g, void* l) {
  __builtin_amdgcn_global_load_lds(
      (const __attribute__((address_space(1))) void*)g,
      (__attribute__((address_space(3))) void*)l, 16, 0, 0);
}

// ---------------------------------------------------------------------------
// prep: one launch does BOTH input casts and all 4 weight transposes.
// grid (4096, 3): y=0 cast x, y=1 cast y, y=2 (x<256) transpose W0..W3.
// ---------------------------------------------------------------------------
__global__ __launch_bounds__(256) void prep(
    const float* __restrict__ x, const float* __restrict__ y,
    const float* __restrict__ W0, const float* __restrict__ W1,
    const float* __restrict__ W2, const float* __restrict__ W3,
    short* __restrict__ xb, short* __restrict__ yb, short* __restrict__ T0,
    short* __restrict__ T1, short* __restrict__ T2, short* __restrict__ T3) {
  const int t = threadIdx.x;
  if (blockIdx.y < 2) {
    const float* src = blockIdx.y ? y : x;
    short* dst = blockIdx.y ? yb : xb;
    size_t i = ((size_t)blockIdx.x * 256 + t) * 4;
    float4 v = *(const float4*)(src + i);
    bf16x4 o;
    o[0] = f2b(v.x); o[1] = f2b(v.y); o[2] = f2b(v.z); o[3] = f2b(v.w);
    *(bf16x4*)(dst + i) = o;
    return;
  }
  const int bx = blockIdx.x;
  if (bx >= 256) return;
  const int wj = bx >> 6, rem = bx & 63;
  const float* W = wj == 0 ? W0 : wj == 1 ? W1 : wj == 2 ? W2 : W3;
  short* T = wj == 0 ? T0 : wj == 1 ? T1 : wj == 2 ? T2 : T3;
  __shared__ float tile[64][65];
  const int k0 = (rem >> 3) * 64, n0 = (rem & 7) * 64;
#pragma unroll
  for (int i = 0; i < 4; ++i) {
    int r = (t >> 4) + i * 16;
    int c = (t & 15) * 4;
    float4 v = *(const float4*)&W[(size_t)(k0 + r) * ND + n0 + c];
    tile[r][c] = v.x; tile[r][c + 1] = v.y;
    tile[r][c + 2] = v.z; tile[r][c + 3] = v.w;
  }
  __syncthreads();
#pragma unroll
  for (int i = 0; i < 4; ++i) {
    int n = (t >> 4) + i * 16;
    int kc = (t & 15) * 4;
    bf16x4 o;
#pragma unroll
    for (int j = 0; j < 4; ++j) o[j] = f2b(tile[kc + j][n]);
    *(bf16x4*)&T[(size_t)(n0 + n) * ND + k0 + kc] = o;
  }
}

// ---------------------------------------------------------------------------
// QKV GEMM: 128x128 tile, 4 waves each 64x64 (acc 4x4), BK=64, single-buffer
// DMA staging (m97 2-barrier), XOR-swizzled LDS (pitch 64, chunk ^= row&7).
// mode 1: bf16 row-major out; 2: bf16 V^T out via LDS-transposed coalesced
// epilogue.
// ---------------------------------------------------------------------------
__device__ __forceinline__ void gemm128(const short* __restrict__ A,
                                        const short* __restrict__ Bt,
                                        short* __restrict__ Cout, int mode,
                                        float alpha) {
  __shared__ short As[128 * 64];
  __shared__ short Bs[128 * 64];
  __shared__ short Tb[64 * 128];  // mode-2 transpose staging [c][r], 16 KB
  const int t = threadIdx.x;
  const int wave = t >> 6, lane = t & 63;
  const int m = lane & 15, quad = lane >> 4;
  const int m0 = blockIdx.y * 128, n0 = blockIdx.x * 128;
  const int mh = (wave >> 1) * 64, nh = (wave & 1) * 64;
  const int r8 = lane >> 3;        // 0..7: row within wave's staging band
  const int c8 = (lane & 7) ^ r8;  // swizzled global chunk for this lane
  const int mx7 = m & 7;           // fragment-read swizzle key
  f32x4 acc[4][4];
#pragma unroll
  for (int i = 0; i < 4; ++i)
#pragma unroll
    for (int j = 0; j < 4; ++j) acc[i][j] = (f32x4){0.f, 0.f, 0.f, 0.f};

  for (int k0 = 0; k0 < ND; k0 += 64) {
    __syncthreads();  // prior iteration's fragment readers done
#pragma unroll
    for (int i = 0; i < 4; ++i) {
      int row = i * 32 + wave * 8 + r8;
      dma16(A + (size_t)(m0 + row) * ND + k0 + c8 * 8,
            As + (i * 256 + wave * 64) * 8);
      dma16(Bt + (size_t)(n0 + row) * ND + k0 + c8 * 8,
            Bs + (i * 256 + wave * 64) * 8);
    }
    __syncthreads();  // drains vmcnt: all DMA visible
    bf16x8 af[4][2], bf[4][2];
#pragma unroll
    for (int mt = 0; mt < 4; ++mt)
#pragma unroll
      for (int kc = 0; kc < 2; ++kc)
        af[mt][kc] = *(const bf16x8*)(As + (mh + mt * 16 + m) * 64 +
                                      ((kc * 4 + quad) ^ mx7) * 8);
#pragma unroll
    for (int nt = 0; nt < 4; ++nt)
#pragma unroll
      for (int kc = 0; kc < 2; ++kc)
        bf[nt][kc] = *(const bf16x8*)(Bs + (nh + nt * 16 + m) * 64 +
                                      ((kc * 4 + quad) ^ mx7) * 8);
#pragma unroll
    for (int mt = 0; mt < 4; ++mt)
#pragma unroll
      for (int nt = 0; nt < 4; ++nt)
#pragma unroll
        for (int kc = 0; kc < 2; ++kc)
          acc[mt][nt] = __builtin_amdgcn_mfma_f32_16x16x32_bf16(
              af[mt][kc], bf[nt][kc], acc[mt][nt], 0, 0, 0);
  }
  if (mode == 2) {
    // V^T epilogue: two 64-col passes through Tb[c][r], then each thread
    // writes 64 B of s-contiguous V^T (256 B contiguous per channel row).
    const int h0 = n0 >> 6;                        // n0 is 128-aligned
    const int b_ = m0 >> 11, s0g = m0 & (NS - 1);  // 128-row tile: one b
#pragma unroll
    for (int p = 0; p < 2; ++p) {
      __syncthreads();  // Tb free (p0: main loop done; p1: p0 readers done)
      if ((wave & 1) == p) {
        // wave's cols nh + nt*16 + m, nh == p*64 -> local c = nt*16 + m
#pragma unroll
        for (int mt = 0; mt < 4; ++mt)
#pragma unroll
          for (int nt = 0; nt < 4; ++nt)
#pragma unroll
            for (int r = 0; r < 4; ++r)
              Tb[(nt * 16 + m) * 128 + mh + mt * 16 + quad * 4 + r] =
                  f2b(acc[mt][nt][r] * alpha);
      }
      __syncthreads();
      {
        int c = t >> 2, sc = (t & 3) * 32;  // c: 0..63, sc: 0/32/64/96
        int gcol = p * 64 + c;
        int h_ = h0 + (gcol >> 6), d_ = gcol & (DEP - 1);
        short* dst =
            Cout + (size_t)((b_ * NH + h_) * DEP + d_) * NS + s0g + sc;
        const short* src = Tb + c * 128 + sc;
#pragma unroll
        for (int i = 0; i < 4; ++i)
          *(bf16x8*)(dst + i * 8) = *(const bf16x8*)(src + i * 8);
      }
    }
  } else {
#pragma unroll
    for (int mt = 0; mt < 4; ++mt)
#pragma unroll
      for (int nt = 0; nt < 4; ++nt)
#pragma unroll
        for (int r = 0; r < 4; ++r) {
          int row = m0 + mh + mt * 16 + quad * 4 + r;
          int col = n0 + nh + nt * 16 + m;
          Cout[(size_t)row * ND + col] = f2b(acc[mt][nt][r] * alpha);
        }
  }
}

__global__ __launch_bounds__(256) void qkv_gemm(
    const short* __restrict__ xb, const short* __restrict__ yb,
    const short* __restrict__ Wqt, const short* __restrict__ Wkt,
    const short* __restrict__ Wvt, short* __restrict__ Qb,
    short* __restrict__ Kb, short* __restrict__ Vtb) {
  if (blockIdx.z == 0)
    gemm128(xb, Wqt, Qb, 1, QSCALE);  // scale + log2e folded into Q
  else if (blockIdx.z == 1)
    gemm128(yb, Wkt, Kb, 1, 1.0f);
  else
    gemm128(yb, Wvt, Vtb, 2, 1.0f);
}

// ---------------------------------------------------------------------------
// Output GEMM: 128x64 tile, BK=64, double-buffered DMA, swizzled LDS,
// fp32 row-major out.  Grid 512 = 2 blocks/CU.
// ---------------------------------------------------------------------------
__global__ __launch_bounds__(256) void out_gemm(const short* __restrict__ A,
                                                const short* __restrict__ Bt,
                                                float* __restrict__ Cout) {
  __shared__ short As[2][128 * 64];
  __shared__ short Bs[2][64 * 64];
  const int t = threadIdx.x;
  const int wave = t >> 6, lane = t & 63;
  const int m = lane & 15, quad = lane >> 4;
  const int m0 = blockIdx.y * 128, n0 = blockIdx.x * 64;
  const int mh = (wave >> 1) * 64, nh = (wave & 1) * 32;
  const int r8 = lane >> 3;
  const int c8 = (lane & 7) ^ r8;
  const int mx7 = m & 7;
  f32x4 acc[4][2];
#pragma unroll
  for (int i = 0; i < 4; ++i)
#pragma unroll
    for (int j = 0; j < 2; ++j) acc[i][j] = (f32x4){0.f, 0.f, 0.f, 0.f};

#pragma unroll
  for (int i = 0; i < 4; ++i)
    dma16(A + (size_t)(m0 + i * 32 + wave * 8 + r8) * ND + c8 * 8,
          As[0] + (i * 256 + wave * 64) * 8);
#pragma unroll
  for (int i = 0; i < 2; ++i)
    dma16(Bt + (size_t)(n0 + i * 32 + wave * 8 + r8) * ND + c8 * 8,
          Bs[0] + (i * 256 + wave * 64) * 8);

  int buf = 0;
  for (int k0 = 0; k0 < ND; k0 += 64, buf ^= 1) {
    __syncthreads();
    if (k0 + 64 < ND) {
#pragma unroll
      for (int i = 0; i < 4; ++i)
        dma16(A + (size_t)(m0 + i * 32 + wave * 8 + r8) * ND + k0 + 64 + c8 * 8,
              As[buf ^ 1] + (i * 256 + wave * 64) * 8);
#pragma unroll
      for (int i = 0; i < 2; ++i)
        dma16(Bt + (size_t)(n0 + i * 32 + wave * 8 + r8) * ND + k0 + 64 +
                  c8 * 8,
              Bs[buf ^ 1] + (i * 256 + wave * 64) * 8);
    }
    bf16x8 af[4][2], bf[2][2];
#pragma unroll
    for (int mt = 0; mt < 4; ++mt)
#pragma unroll
      for (int kc = 0; kc < 2; ++kc)
        af[mt][kc] = *(const bf16x8*)(As[buf] + (mh + mt * 16 + m) * 64 +
                                      ((kc * 4 + quad) ^ mx7) * 8);
#pragma unroll
    for (int nt = 0; nt < 2; ++nt)
#pragma unroll
      for (int kc = 0; kc < 2; ++kc)
        bf[nt][kc] = *(const bf16x8*)(Bs[buf] + (nh + nt * 16 + m) * 64 +
                                      ((kc * 4 + quad) ^ mx7) * 8);
#pragma unroll
    for (int mt = 0; mt < 4; ++mt)
#pragma unroll
      for (int nt = 0; nt < 2; ++nt)
#pragma unroll
        for (int kc = 0; kc < 2; ++kc)
          acc[mt][nt] = __builtin_amdgcn_mfma_f32_16x16x32_bf16(
              af[mt][kc], bf[nt][kc], acc[mt][nt], 0, 0, 0);
  }
#pragma unroll
  for (int mt = 0; mt < 4; ++mt)
#pragma unroll
    for (int nt = 0; nt < 2; ++nt)
#pragma unroll
      for (int r = 0; r < 4; ++r) {
        int row = m0 + mh + mt * 16 + quad * 4 + r;
        int col = n0 + nh + nt * 16 + m;
        Cout[(size_t)row * ND + col] = acc[mt][nt][r];
      }
}

// ---------------------------------------------------------------------------
// Flash attention, S^T formulation, 32x32x16 MFMA, in-register softmax,
// IN-BLOCK kv-split x2 (8 waves: 0-3 kv[0,1024), 4-7 kv[1024,2048)).
// KVBLK=128: TWO 64-kv sub-tiles staged and computed per barrier pair --
// halves barrier/drain events (32 -> 16 per block) and lets the scheduler
// overlap QK(sub1) MFMAs into PV(sub0)'s latency shadow WITHIN one barrier
// region (no cross-barrier register state -- the r4-r6 spill trap does not
// apply; St/pf are declared inside the sub loop and reused).
// LDS 64.5 KB (free: residency is register-capped at 2 blocks/CU -- VGPR 64
// + ~64 AGPR = 128/thread, r9 finding).  Single-buffer m97 2-barrier.
// Max-free softmax partials combine exactly in LDS: O=(O0+O1)/(l0+l1).
// ---------------------------------------------------------------------------
__global__ __launch_bounds__(512, 4) void attn_mfma(
    const short* __restrict__ Qb, const short* __restrict__ Kb,
    const short* __restrict__ Vtb, short* __restrict__ Ob) {
  __shared__ short KVs[2][2][2][64 * 64];  // [K=0/V=1][zh][sub], 64 KB
  __shared__ float lxs[128];               // cross-zh l exchange
  const int t = threadIdx.x;
  const int wave = t >> 6, lane = t & 63;
  const int zh = wave >> 2, wl = wave & 3;  // kv-half, q-subtile
  const int l31 = lane & 31, hi = lane >> 5;
  const int sw = lane & 7;  // fragment-read swizzle key (row&7 == lane&7)
  const int bh = blockIdx.y, b = bh >> 3, h = bh & 7;
  const int q0 = blockIdx.x * 128 + wl * 32;
  const int kvb = zh * KVHALF;
  const size_t rowb = (size_t)b * NS;
  const short* Vtbase = Vtb + (size_t)(bh * DEP) * NS;
  const int r8 = lane >> 3;
  const int c8 = (lane & 7) ^ r8;

  // Q fragments (B-operand): col=q=l31, k(d) = dc*16 + hi*8 + j
  bf16x8 qf[4];
#pragma unroll
  for (int dc = 0; dc < 4; ++dc)
    qf[dc] = *(const bf16x8*)(Qb + (rowb + q0 + l31) * ND + h * DEP + dc * 16 +
                              hi * 8);

  // loop-invariant zero C-operand: avoids 32 v_mov per iteration (St init)
  f32x16 kzero;
#pragma unroll
  for (int i = 0; i < 16; ++i) kzero[i] = 0.f;

  float l_ = 0.0f;
  f32x16 Ot[2];
#pragma unroll
  for (int dt = 0; dt < 2; ++dt)
#pragma unroll
    for (int i = 0; i < 16; ++i) Ot[dt][i] = 0.f;

  for (int kv0 = 0; kv0 < KVHALF; kv0 += 128) {
    __syncthreads();  // prior iteration's fragment readers done
#pragma unroll
    for (int sub = 0; sub < 2; ++sub)
#pragma unroll
      for (int i = 0; i < 2; ++i) {
        int row = i * 32 + wl * 8 + r8;
        dma16(Kb + (rowb + kvb + kv0 + sub * 64 + row) * ND + h * DEP + c8 * 8,
              &KVs[0][zh][sub][(i * 256 + wl * 64) * 8]);
        dma16(Vtbase + (size_t)row * NS + kvb + kv0 + sub * 64 + c8 * 8,
              &KVs[1][zh][sub][(i * 256 + wl * 64) * 8]);
      }
    __syncthreads();  // drains vmcnt: both sub-tiles visible

#pragma unroll
    for (int sub = 0; sub < 2; ++sub) {
      const short* Ksb = &KVs[0][zh][sub][0];
      const short* Vsb = &KVs[1][zh][sub][0];

      // QK^T: St[kt] = S^T tile (kv = kt*32+row, q = col = l31)
      f32x16 St[2];
#pragma unroll
      for (int kt = 0; kt < 2; ++kt) {
        bf16x8 kf0 = *(const bf16x8*)(Ksb + (kt * 32 + l31) * 64 +
                                      (hi ^ sw) * 8);
        St[kt] = __builtin_amdgcn_mfma_f32_32x32x16_bf16(kf0, qf[0], kzero,
                                                         0, 0, 0);
#pragma unroll
        for (int dc = 1; dc < 4; ++dc) {
          bf16x8 kf = *(const bf16x8*)(Ksb + (kt * 32 + l31) * 64 +
                                       ((dc * 2 + hi) ^ sw) * 8);
          St[kt] = __builtin_amdgcn_mfma_f32_32x32x16_bf16(kf, qf[dc], St[kt],
                                                           0, 0, 0);
        }
      }

      // softmax (max-free, exp2) + in-register P^T -> B-fragment assembly.
      // St reg r (tile kt): kv = kt*32 + (r&3) + 8*(r>>2) + 4*hi.
      // B-frag slice s needs: elem j = P[s*16 + hi*8 + j][q].
      bf16x8 pf[4];
      float rs = 0.f;
#pragma unroll
      for (int s = 0; s < 4; ++s) {
        const int kt = s >> 1, base = (s & 1) * 8;
        float E[8];
#pragma unroll
        for (int j = 0; j < 8; ++j) {
          E[j] = __builtin_amdgcn_exp2f(St[kt][base + j]);
        }
        rs += ((E[0] + E[1]) + (E[2] + E[3])) +
              ((E[4] + E[5]) + (E[6] + E[7]));
        unsigned A0 = pk2(E[0], E[1]), A1 = pk2(E[2], E[3]);
        unsigned A2 = pk2(E[4], E[5]), A3 = pk2(E[6], E[7]);
        // swap: out0 = [a.lo | b.lo], out1 = [a.hi | b.hi]
        auto r02 =
            __builtin_amdgcn_permlane32_swap((int)A0, (int)A2, false, false);
        auto r13 =
            __builtin_amdgcn_permlane32_swap((int)A1, (int)A3, false, false);
        union { bf16x8 v; int u[4]; } pu;
        pu.u[0] = r02[0]; pu.u[1] = r13[0]; pu.u[2] = r02[1];
        pu.u[3] = r13[1];
        pf[s] = pu.v;
      }
      l_ += rs;

      // PV: Ot^T[dt] += V^T[d, kv-slice] * P^T[kv-slice, q]
#pragma unroll
      for (int dt = 0; dt < 2; ++dt)
#pragma unroll
        for (int s = 0; s < 4; ++s) {
          bf16x8 vf = *(const bf16x8*)(Vsb + (dt * 32 + l31) * 64 +
                                       ((s * 2 + hi) ^ sw) * 8);
          Ot[dt] = __builtin_amdgcn_mfma_f32_32x32x16_bf16(vf, pf[s], Ot[dt],
                                                           0, 0, 0);
        }
    }
  }

  // per-wave denominator partial: lane l and l^32 hold complementary kv sets
  l_ += __shfl_xor(l_, 32, 64);

  // cross-half combine in LDS (aliased over dead K/V staging buffers).
  __syncthreads();  // all K/V fragment reads of the last tile complete
  float* Ox = (float*)KVs;  // [4][64][32] fp32 = 32 KB (first half of KVs)
  if (zh == 1) {
#pragma unroll
    for (int dt = 0; dt < 2; ++dt)
#pragma unroll
      for (int r = 0; r < 16; ++r) {
        int d = dt * 32 + (r & 3) + 8 * (r >> 2) + 4 * hi;
        Ox[(wl * 64 + d) * 32 + l31] = Ot[dt][r];
      }
    if (lane < 32) lxs[wl * 32 + l31] = l_;
  }
  __syncthreads();
  if (zh == 0) {
    float linv = 1.0f / (l_ + lxs[wl * 32 + l31]);
    size_t row = rowb + q0 + l31;
    // Ot reg r (tile dt): d = dt*32 + (r&3) + 8*(r>>2) + 4*hi -> 8B stores
#pragma unroll
    for (int dt = 0; dt < 2; ++dt)
#pragma unroll
      for (int g = 0; g < 4; ++g) {
        int d0 = dt * 32 + g * 8 + hi * 4;
        float o[4];
#pragma unroll
        for (int j = 0; j < 4; ++j)
          o[j] = Ot[dt][g * 4 + j] + Ox[(wl * 64 + d0 + j) * 32 + l31];
        uint2 pk;
        pk.x = pk2(o[0] * linv, o[1] * linv);
        pk.y = pk2(o[2] * linv, o[3] * linv);
        *(uint2*)(Ob + row * ND + h * DEP + d0) = pk;
      }
  }
}

// ---------------------------------------------------------------------------
extern "C" void kernel_launch(void* const* d_in, const int* in_sizes, int n_in,
                              void* d_out, int out_size, void* d_ws,
                              size_t ws_size, hipStream_t stream) {
  const float* x = (const float*)d_in[0];
  const float* y = (const float*)d_in[1];
  const float* Wq = (const float*)d_in[2];
  const float* Wk = (const float*)d_in[3];
  const float* Wv = (const float*)d_in[4];
  const float* Wo = (const float*)d_in[5];
  float* out = (float*)d_out;

  const size_t mat = (size_t)NB * NS * ND;
  const size_t wsz = (size_t)ND * ND;
  short* xb = (short*)d_ws;
  short* yb = xb + mat;
  short* Wqt = yb + mat;
  short* Wkt = Wqt + wsz;
  short* Wvt = Wkt + wsz;
  short* Wot = Wvt + wsz;
  short* Qb = Wot + wsz;
  short* Kb = Qb + mat;
  short* Vtb = Kb + mat;
  short* attnb = xb;  // reuse: xb dead after QKV GEMM

  prep<<<dim3(mat / 1024, 3), 256, 0, stream>>>(x, y, Wq, Wk, Wv, Wo, xb, yb,
                                                Wqt, Wkt, Wvt, Wot);
  qkv_gemm<<<dim3(ND / 128, (NB * NS) / 128, 3), 256, 0, stream>>>(
      xb, yb, Wqt, Wkt, Wvt, Qb, Kb, Vtb);
  attn_mfma<<<dim3(NS / 128, NB * NH), 512, 0, stream>>>(Qb, Kb, Vtb, attnb);
  out_gemm<<<dim3(ND / 64, (NB * NS) / 128), 256, 0, stream>>>(attnb, Wot,
                                                               out);
}

// Round 11
// 180.101 us; speedup vs baseline: 1.0710x; 1.0176x over previous
//
#include <hip/hip_runtime.h>
#include <hip/hip_bf16.h>
#include <math.h>
#include <stdint.h>

#define NB 4
#define NS 2048
#define ND 512
#define NH 8
#define DEP 64
#define KVHALF (NS / 2)

typedef __attribute__((ext_vector_type(8))) short bf16x8;
typedef __attribute__((ext_vector_type(4))) short bf16x4;
typedef __attribute__((ext_vector_type(4))) float f32x4;
typedef __attribute__((ext_vector_type(16))) float f32x16;

#define QSCALE 0.18033688011112042f  // DEPTH^-0.5 * log2(e): softmax in exp2

__device__ __forceinline__ short f2b(float f) {
  unsigned u = __float_as_uint(f);
  u += 0x7FFF + ((u >> 16) & 1);  // RNE
  return (short)(u >> 16);
}
__device__ __forceinline__ unsigned pk2(float a, float b) {
  union { __hip_bfloat162 h; unsigned u; } c;
  c.h = __float22bfloat162_rn(float2{a, b});
  return c.u;
}
// async 16B global->LDS DMA; LDS dest is wave-uniform base + lane*16
__device__ __forceinline__ void dma16(const void* g, void* l) {
  __builtin_amdgcn_global_load_lds(
      (const __attribute__((address_space(1))) void*)g,
      (__attribute__((address_space(3))) void*)l, 16, 0, 0);
}

// ---------------------------------------------------------------------------
// prep: one launch does BOTH input casts and all 4 weight transposes.
// grid (4096, 3): y=0 cast x, y=1 cast y, y=2 (x<256) transpose W0..W3.
// ---------------------------------------------------------------------------
__global__ __launch_bounds__(256) void prep(
    const float* __restrict__ x, const float* __restrict__ y,
    const float* __restrict__ W0, const float* __restrict__ W1,
    const float* __restrict__ W2, const float* __restrict__ W3,
    short* __restrict__ xb, short* __restrict__ yb, short* __restrict__ T0,
    short* __restrict__ T1, short* __restrict__ T2, short* __restrict__ T3) {
  const int t = threadIdx.x;
  if (blockIdx.y < 2) {
    const float* src = blockIdx.y ? y : x;
    short* dst = blockIdx.y ? yb : xb;
    size_t i = ((size_t)blockIdx.x * 256 + t) * 4;
    float4 v = *(const float4*)(src + i);
    bf16x4 o;
    o[0] = f2b(v.x); o[1] = f2b(v.y); o[2] = f2b(v.z); o[3] = f2b(v.w);
    *(bf16x4*)(dst + i) = o;
    return;
  }
  const int bx = blockIdx.x;
  if (bx >= 256) return;
  const int wj = bx >> 6, rem = bx & 63;
  const float* W = wj == 0 ? W0 : wj == 1 ? W1 : wj == 2 ? W2 : W3;
  short* T = wj == 0 ? T0 : wj == 1 ? T1 : wj == 2 ? T2 : T3;
  __shared__ float tile[64][65];
  const int k0 = (rem >> 3) * 64, n0 = (rem & 7) * 64;
#pragma unroll
  for (int i = 0; i < 4; ++i) {
    int r = (t >> 4) + i * 16;
    int c = (t & 15) * 4;
    float4 v = *(const float4*)&W[(size_t)(k0 + r) * ND + n0 + c];
    tile[r][c] = v.x; tile[r][c + 1] = v.y;
    tile[r][c + 2] = v.z; tile[r][c + 3] = v.w;
  }
  __syncthreads();
#pragma unroll
  for (int i = 0; i < 4; ++i) {
    int n = (t >> 4) + i * 16;
    int kc = (t & 15) * 4;
    bf16x4 o;
#pragma unroll
    for (int j = 0; j < 4; ++j) o[j] = f2b(tile[kc + j][n]);
    *(bf16x4*)&T[(size_t)(n0 + n) * ND + k0 + kc] = o;
  }
}

// ---------------------------------------------------------------------------
// QKV GEMM: 128x128 tile, 4 waves each 64x64 (acc 4x4), BK=64, single-buffer
// DMA staging (m97 2-barrier), XOR-swizzled LDS (pitch 64, chunk ^= row&7).
// mode 1: bf16 row-major out; 2: bf16 V^T out via LDS-transposed coalesced
// epilogue.
// ---------------------------------------------------------------------------
__device__ __forceinline__ void gemm128(const short* __restrict__ A,
                                        const short* __restrict__ Bt,
                                        short* __restrict__ Cout, int mode,
                                        float alpha) {
  __shared__ short As[128 * 64];
  __shared__ short Bs[128 * 64];
  __shared__ short Tb[64 * 128];  // mode-2 transpose staging [c][r], 16 KB
  const int t = threadIdx.x;
  const int wave = t >> 6, lane = t & 63;
  const int m = lane & 15, quad = lane >> 4;
  const int m0 = blockIdx.y * 128, n0 = blockIdx.x * 128;
  const int mh = (wave >> 1) * 64, nh = (wave & 1) * 64;
  const int r8 = lane >> 3;        // 0..7: row within wave's staging band
  const int c8 = (lane & 7) ^ r8;  // swizzled global chunk for this lane
  const int mx7 = m & 7;           // fragment-read swizzle key
  f32x4 acc[4][4];
#pragma unroll
  for (int i = 0; i < 4; ++i)
#pragma unroll
    for (int j = 0; j < 4; ++j) acc[i][j] = (f32x4){0.f, 0.f, 0.f, 0.f};

  for (int k0 = 0; k0 < ND; k0 += 64) {
    __syncthreads();  // prior iteration's fragment readers done
#pragma unroll
    for (int i = 0; i < 4; ++i) {
      int row = i * 32 + wave * 8 + r8;
      dma16(A + (size_t)(m0 + row) * ND + k0 + c8 * 8,
            As + (i * 256 + wave * 64) * 8);
      dma16(Bt + (size_t)(n0 + row) * ND + k0 + c8 * 8,
            Bs + (i * 256 + wave * 64) * 8);
    }
    __syncthreads();  // drains vmcnt: all DMA visible
    bf16x8 af[4][2], bf[4][2];
#pragma unroll
    for (int mt = 0; mt < 4; ++mt)
#pragma unroll
      for (int kc = 0; kc < 2; ++kc)
        af[mt][kc] = *(const bf16x8*)(As + (mh + mt * 16 + m) * 64 +
                                      ((kc * 4 + quad) ^ mx7) * 8);
#pragma unroll
    for (int nt = 0; nt < 4; ++nt)
#pragma unroll
      for (int kc = 0; kc < 2; ++kc)
        bf[nt][kc] = *(const bf16x8*)(Bs + (nh + nt * 16 + m) * 64 +
                                      ((kc * 4 + quad) ^ mx7) * 8);
#pragma unroll
    for (int mt = 0; mt < 4; ++mt)
#pragma unroll
      for (int nt = 0; nt < 4; ++nt)
#pragma unroll
        for (int kc = 0; kc < 2; ++kc)
          acc[mt][nt] = __builtin_amdgcn_mfma_f32_16x16x32_bf16(
              af[mt][kc], bf[nt][kc], acc[mt][nt], 0, 0, 0);
  }
  if (mode == 2) {
    // V^T epilogue: two 64-col passes through Tb[c][r], then each thread
    // writes 64 B of s-contiguous V^T (256 B contiguous per channel row).
    const int h0 = n0 >> 6;                        // n0 is 128-aligned
    const int b_ = m0 >> 11, s0g = m0 & (NS - 1);  // 128-row tile: one b
#pragma unroll
    for (int p = 0; p < 2; ++p) {
      __syncthreads();  // Tb free (p0: main loop done; p1: p0 readers done)
      if ((wave & 1) == p) {
        // wave's cols nh + nt*16 + m, nh == p*64 -> local c = nt*16 + m
#pragma unroll
        for (int mt = 0; mt < 4; ++mt)
#pragma unroll
          for (int nt = 0; nt < 4; ++nt)
#pragma unroll
            for (int r = 0; r < 4; ++r)
              Tb[(nt * 16 + m) * 128 + mh + mt * 16 + quad * 4 + r] =
                  f2b(acc[mt][nt][r] * alpha);
      }
      __syncthreads();
      {
        int c = t >> 2, sc = (t & 3) * 32;  // c: 0..63, sc: 0/32/64/96
        int gcol = p * 64 + c;
        int h_ = h0 + (gcol >> 6), d_ = gcol & (DEP - 1);
        short* dst =
            Cout + (size_t)((b_ * NH + h_) * DEP + d_) * NS + s0g + sc;
        const short* src = Tb + c * 128 + sc;
#pragma unroll
        for (int i = 0; i < 4; ++i)
          *(bf16x8*)(dst + i * 8) = *(const bf16x8*)(src + i * 8);
      }
    }
  } else {
#pragma unroll
    for (int mt = 0; mt < 4; ++mt)
#pragma unroll
      for (int nt = 0; nt < 4; ++nt)
#pragma unroll
        for (int r = 0; r < 4; ++r) {
          int row = m0 + mh + mt * 16 + quad * 4 + r;
          int col = n0 + nh + nt * 16 + m;
          Cout[(size_t)row * ND + col] = f2b(acc[mt][nt][r] * alpha);
        }
  }
}

__global__ __launch_bounds__(256) void qkv_gemm(
    const short* __restrict__ xb, const short* __restrict__ yb,
    const short* __restrict__ Wqt, const short* __restrict__ Wkt,
    const short* __restrict__ Wvt, short* __restrict__ Qb,
    short* __restrict__ Kb, short* __restrict__ Vtb) {
  if (blockIdx.z == 0)
    gemm128(xb, Wqt, Qb, 1, QSCALE);  // scale + log2e folded into Q
  else if (blockIdx.z == 1)
    gemm128(yb, Wkt, Kb, 1, 1.0f);
  else
    gemm128(yb, Wvt, Vtb, 2, 1.0f);
}

// ---------------------------------------------------------------------------
// Output GEMM: 128x64 tile, BK=64, double-buffered DMA, swizzled LDS,
// fp32 row-major out.  Grid 512 = 2 blocks/CU.
// ---------------------------------------------------------------------------
__global__ __launch_bounds__(256) void out_gemm(const short* __restrict__ A,
                                                const short* __restrict__ Bt,
                                                float* __restrict__ Cout) {
  __shared__ short As[2][128 * 64];
  __shared__ short Bs[2][64 * 64];
  const int t = threadIdx.x;
  const int wave = t >> 6, lane = t & 63;
  const int m = lane & 15, quad = lane >> 4;
  const int m0 = blockIdx.y * 128, n0 = blockIdx.x * 64;
  const int mh = (wave >> 1) * 64, nh = (wave & 1) * 32;
  const int r8 = lane >> 3;
  const int c8 = (lane & 7) ^ r8;
  const int mx7 = m & 7;
  f32x4 acc[4][2];
#pragma unroll
  for (int i = 0; i < 4; ++i)
#pragma unroll
    for (int j = 0; j < 2; ++j) acc[i][j] = (f32x4){0.f, 0.f, 0.f, 0.f};

#pragma unroll
  for (int i = 0; i < 4; ++i)
    dma16(A + (size_t)(m0 + i * 32 + wave * 8 + r8) * ND + c8 * 8,
          As[0] + (i * 256 + wave * 64) * 8);
#pragma unroll
  for (int i = 0; i < 2; ++i)
    dma16(Bt + (size_t)(n0 + i * 32 + wave * 8 + r8) * ND + c8 * 8,
          Bs[0] + (i * 256 + wave * 64) * 8);

  int buf = 0;
  for (int k0 = 0; k0 < ND; k0 += 64, buf ^= 1) {
    __syncthreads();
    if (k0 + 64 < ND) {
#pragma unroll
      for (int i = 0; i < 4; ++i)
        dma16(A + (size_t)(m0 + i * 32 + wave * 8 + r8) * ND + k0 + 64 + c8 * 8,
              As[buf ^ 1] + (i * 256 + wave * 64) * 8);
#pragma unroll
      for (int i = 0; i < 2; ++i)
        dma16(Bt + (size_t)(n0 + i * 32 + wave * 8 + r8) * ND + k0 + 64 +
                  c8 * 8,
              Bs[buf ^ 1] + (i * 256 + wave * 64) * 8);
    }
    bf16x8 af[4][2], bf[2][2];
#pragma unroll
    for (int mt = 0; mt < 4; ++mt)
#pragma unroll
      for (int kc = 0; kc < 2; ++kc)
        af[mt][kc] = *(const bf16x8*)(As[buf] + (mh + mt * 16 + m) * 64 +
                                      ((kc * 4 + quad) ^ mx7) * 8);
#pragma unroll
    for (int nt = 0; nt < 2; ++nt)
#pragma unroll
      for (int kc = 0; kc < 2; ++kc)
        bf[nt][kc] = *(const bf16x8*)(Bs[buf] + (nh + nt * 16 + m) * 64 +
                                      ((kc * 4 + quad) ^ mx7) * 8);
#pragma unroll
    for (int mt = 0; mt < 4; ++mt)
#pragma unroll
      for (int nt = 0; nt < 2; ++nt)
#pragma unroll
        for (int kc = 0; kc < 2; ++kc)
          acc[mt][nt] = __builtin_amdgcn_mfma_f32_16x16x32_bf16(
              af[mt][kc], bf[nt][kc], acc[mt][nt], 0, 0, 0);
  }
#pragma unroll
  for (int mt = 0; mt < 4; ++mt)
#pragma unroll
    for (int nt = 0; nt < 2; ++nt)
#pragma unroll
      for (int r = 0; r < 4; ++r) {
        int row = m0 + mh + mt * 16 + quad * 4 + r;
        int col = n0 + nh + nt * 16 + m;
        Cout[(size_t)row * ND + col] = acc[mt][nt][r];
      }
}

// ---------------------------------------------------------------------------
// Flash attention (r8 body), S^T formulation, 32x32x16 MFMA, in-register
// softmax, in-block kv-split x2, single-buffered K/V (m97 2-barrier),
// 32.5 KB LDS.  NEW: XCD-aware work remap (T1) -- linear block id L is
// reinterpreted as (xcd = L&7, qx, bh-sub) so all 16 q-blocks of one bh
// land on ONE XCD (assuming HW round-robins linear id % 8; if not, only
// locality changes, never correctness).  K/V working set per XCD = 4 bh x
// 512 KB = 2 MB <= 4 MB L2 -> K/V re-reads become L2 hits (~200cy) instead
// of HBM re-fetches (~900cy).  Each kv-iteration drains vmcnt at the
// barrier, so staged-load latency is on the critical path 16x/block.
// Max-free softmax partials combine exactly in LDS: O=(O0+O1)/(l0+l1).
// ---------------------------------------------------------------------------
__global__ __launch_bounds__(512, 4) void attn_mfma(
    const short* __restrict__ Qb, const short* __restrict__ Kb,
    const short* __restrict__ Vtb, short* __restrict__ Ob) {
  __shared__ short KVs[2][2][64 * 64];  // [K=0/V=1][zh][kv/d tile], 32 KB
  __shared__ float lxs[128];            // cross-half l exchange
  const int t = threadIdx.x;
  const int wave = t >> 6, lane = t & 63;
  const int zh = wave >> 2, wl = wave & 3;  // kv-half, q-subtile
  const int l31 = lane & 31, hi = lane >> 5;
  const int sw = lane & 7;  // fragment-read swizzle key (row&7 == lane&7)
  // XCD-aware remap: L[2:0]=xcd, L[6:3]=q-tile, L[8:7]=bh-within-XCD.
  // bh = xcd*4 + L[8:7] -> blocks sharing bh share an XCD (bijective).
  const int L = blockIdx.y * 16 + blockIdx.x;
  const int bh = (L & 7) * 4 + (L >> 7);
  const int qx = (L >> 3) & 15;
  const int b = bh >> 3, h = bh & 7;
  const int q0 = qx * 128 + wl * 32;
  const int kvb = zh * KVHALF;
  const size_t rowb = (size_t)b * NS;
  const short* Vtbase = Vtb + (size_t)(bh * DEP) * NS;
  const int r8 = lane >> 3;
  const int c8 = (lane & 7) ^ r8;
  short* Ksb = &KVs[0][zh][0];
  short* Vsb = &KVs[1][zh][0];

  // Q fragments (B-operand): col=q=l31, k(d) = dc*16 + hi*8 + j
  bf16x8 qf[4];
#pragma unroll
  for (int dc = 0; dc < 4; ++dc)
    qf[dc] = *(const bf16x8*)(Qb + (rowb + q0 + l31) * ND + h * DEP + dc * 16 +
                              hi * 8);

  // loop-invariant zero C-operand: avoids 32 v_mov per iteration (St init)
  f32x16 kzero;
#pragma unroll
  for (int i = 0; i < 16; ++i) kzero[i] = 0.f;

  float l_ = 0.0f;
  f32x16 Ot[2];
#pragma unroll
  for (int dt = 0; dt < 2; ++dt)
#pragma unroll
    for (int i = 0; i < 16; ++i) Ot[dt][i] = 0.f;

  for (int kv0 = 0; kv0 < KVHALF; kv0 += 64) {
    __syncthreads();  // prior iteration's fragment readers done
#pragma unroll
    for (int i = 0; i < 2; ++i) {
      int row = i * 32 + wl * 8 + r8;
      dma16(Kb + (rowb + kvb + kv0 + row) * ND + h * DEP + c8 * 8,
            Ksb + (i * 256 + wl * 64) * 8);
      dma16(Vtbase + (size_t)row * NS + kvb + kv0 + c8 * 8,
            Vsb + (i * 256 + wl * 64) * 8);
    }
    __syncthreads();  // drains vmcnt: K/V tiles visible

    // QK^T: St[kt] = S^T tile (kv = kt*32+row, q = col = l31)
    f32x16 St[2];
#pragma unroll
    for (int kt = 0; kt < 2; ++kt) {
      bf16x8 kf0 = *(const bf16x8*)(Ksb + (kt * 32 + l31) * 64 +
                                    (hi ^ sw) * 8);
      St[kt] = __builtin_amdgcn_mfma_f32_32x32x16_bf16(kf0, qf[0], kzero,
                                                       0, 0, 0);
#pragma unroll
      for (int dc = 1; dc < 4; ++dc) {
        bf16x8 kf = *(const bf16x8*)(Ksb + (kt * 32 + l31) * 64 +
                                     ((dc * 2 + hi) ^ sw) * 8);
        St[kt] = __builtin_amdgcn_mfma_f32_32x32x16_bf16(kf, qf[dc], St[kt],
                                                         0, 0, 0);
      }
    }

    // softmax (max-free, exp2) + in-register P^T -> B-fragment assembly.
    // St reg r (tile kt): kv = kt*32 + (r&3) + 8*(r>>2) + 4*hi.
    // B-frag slice s needs: elem j = P[kv0 + s*16 + hi*8 + j][q].
    bf16x8 pf[4];
    float rs = 0.f;
#pragma unroll
    for (int s = 0; s < 4; ++s) {
      const int kt = s >> 1, base = (s & 1) * 8;
      float E[8];
#pragma unroll
      for (int j = 0; j < 8; ++j) {
        E[j] = __builtin_amdgcn_exp2f(St[kt][base + j]);
      }
      rs += ((E[0] + E[1]) + (E[2] + E[3])) + ((E[4] + E[5]) + (E[6] + E[7]));
      unsigned A0 = pk2(E[0], E[1]), A1 = pk2(E[2], E[3]);
      unsigned A2 = pk2(E[4], E[5]), A3 = pk2(E[6], E[7]);
      // swap: out0 = [a.lo | b.lo], out1 = [a.hi | b.hi]
      auto r02 =
          __builtin_amdgcn_permlane32_swap((int)A0, (int)A2, false, false);
      auto r13 =
          __builtin_amdgcn_permlane32_swap((int)A1, (int)A3, false, false);
      union { bf16x8 v; int u[4]; } pu;
      pu.u[0] = r02[0]; pu.u[1] = r13[0]; pu.u[2] = r02[1]; pu.u[3] = r13[1];
      pf[s] = pu.v;
    }
    l_ += rs;

    // PV: Ot^T[dt] += V^T[d, kv-slice] * P^T[kv-slice, q]
#pragma unroll
    for (int dt = 0; dt < 2; ++dt)
#pragma unroll
      for (int s = 0; s < 4; ++s) {
        bf16x8 vf = *(const bf16x8*)(Vsb + (dt * 32 + l31) * 64 +
                                     ((s * 2 + hi) ^ sw) * 8);
        Ot[dt] = __builtin_amdgcn_mfma_f32_32x32x16_bf16(vf, pf[s], Ot[dt],
                                                         0, 0, 0);
      }
  }

  // per-wave denominator partial: lane l and l^32 hold complementary kv sets
  l_ += __shfl_xor(l_, 32, 64);

  // cross-half combine in LDS (aliased over dead K/V staging buffers).
  __syncthreads();  // all K/V fragment reads of the last tile complete
  float* Ox = (float*)KVs;  // [4][64][32] fp32 = 32 KB (spans KVs exactly)
  if (zh == 1) {
#pragma unroll
    for (int dt = 0; dt < 2; ++dt)
#pragma unroll
      for (int r = 0; r < 16; ++r) {
        int d = dt * 32 + (r & 3) + 8 * (r >> 2) + 4 * hi;
        Ox[(wl * 64 + d) * 32 + l31] = Ot[dt][r];
      }
    if (lane < 32) lxs[wl * 32 + l31] = l_;
  }
  __syncthreads();
  if (zh == 0) {
    float linv = 1.0f / (l_ + lxs[wl * 32 + l31]);
    size_t row = rowb + q0 + l31;
    // Ot reg r (tile dt): d = dt*32 + (r&3) + 8*(r>>2) + 4*hi -> 8B stores
#pragma unroll
    for (int dt = 0; dt < 2; ++dt)
#pragma unroll
      for (int g = 0; g < 4; ++g) {
        int d0 = dt * 32 + g * 8 + hi * 4;
        float o[4];
#pragma unroll
        for (int j = 0; j < 4; ++j)
          o[j] = Ot[dt][g * 4 + j] + Ox[(wl * 64 + d0 + j) * 32 + l31];
        uint2 pk;
        pk.x = pk2(o[0] * linv, o[1] * linv);
        pk.y = pk2(o[2] * linv, o[3] * linv);
        *(uint2*)(Ob + row * ND + h * DEP + d0) = pk;
      }
  }
}

// ---------------------------------------------------------------------------
extern "C" void kernel_launch(void* const* d_in, const int* in_sizes, int n_in,
                              void* d_out, int out_size, void* d_ws,
                              size_t ws_size, hipStream_t stream) {
  const float* x = (const float*)d_in[0];
  const float* y = (const float*)d_in[1];
  const float* Wq = (const float*)d_in[2];
  const float* Wk = (const float*)d_in[3];
  const float* Wv = (const float*)d_in[4];
  const float* Wo = (const float*)d_in[5];
  float* out = (float*)d_out;

  const size_t mat = (size_t)NB * NS * ND;
  const size_t wsz = (size_t)ND * ND;
  short* xb = (short*)d_ws;
  short* yb = xb + mat;
  short* Wqt = yb + mat;
  short* Wkt = Wqt + wsz;
  short* Wvt = Wkt + wsz;
  short* Wot = Wvt + wsz;
  short* Qb = Wot + wsz;
  short* Kb = Qb + mat;
  short* Vtb = Kb + mat;
  short* attnb = xb;  // reuse: xb dead after QKV GEMM

  prep<<<dim3(mat / 1024, 3), 256, 0, stream>>>(x, y, Wq, Wk, Wv, Wo, xb, yb,
                                                Wqt, Wkt, Wvt, Wot);
  qkv_gemm<<<dim3(ND / 128, (NB * NS) / 128, 3), 256, 0, stream>>>(
      xb, yb, Wqt, Wkt, Wvt, Qb, Kb, Vtb);
  attn_mfma<<<dim3(NS / 128, NB * NH), 512, 0, stream>>>(Qb, Kb, Vtb, attnb);
  out_gemm<<<dim3(ND / 64, (NB * NS) / 128), 256, 0, stream>>>(attnb, Wot,
                                                               out);
}

// Round 12
// 171.683 us; speedup vs baseline: 1.1235x; 1.0490x over previous
//
#include <hip/hip_runtime.h>
#include <hip/hip_bf16.h>
#include <math.h>
#include <stdint.h>

#define NB 4
#define NS 2048
#define ND 512
#define NH 8
#define DEP 64
#define KVHALF (NS / 2)

typedef __attribute__((ext_vector_type(8))) short bf16x8;
typedef __attribute__((ext_vector_type(4))) short bf16x4;
typedef __attribute__((ext_vector_type(4))) float f32x4;
typedef __attribute__((ext_vector_type(16))) float f32x16;

#define QSCALE 0.18033688011112042f  // DEPTH^-0.5 * log2(e): softmax in exp2

__device__ __forceinline__ short f2b(float f) {
  unsigned u = __float_as_uint(f);
  u += 0x7FFF + ((u >> 16) & 1);  // RNE
  return (short)(u >> 16);
}
__device__ __forceinline__ unsigned pk2(float a, float b) {
  union { __hip_bfloat162 h; unsigned u; } c;
  c.h = __float22bfloat162_rn(float2{a, b});
  return c.u;
}
// async 16B global->LDS DMA; LDS dest is wave-uniform base + lane*16
__device__ __forceinline__ void dma16(const void* g, void* l) {
  __builtin_amdgcn_global_load_lds(
      (const __attribute__((address_space(1))) void*)g,
      (__attribute__((address_space(3))) void*)l, 16, 0, 0);
}

// ---------------------------------------------------------------------------
// prep: one launch does BOTH input casts and all 4 weight transposes.
// grid (4096, 3): y=0 cast x, y=1 cast y, y=2 (x<256) transpose W0..W3.
// ---------------------------------------------------------------------------
__global__ __launch_bounds__(256) void prep(
    const float* __restrict__ x, const float* __restrict__ y,
    const float* __restrict__ W0, const float* __restrict__ W1,
    const float* __restrict__ W2, const float* __restrict__ W3,
    short* __restrict__ xb, short* __restrict__ yb, short* __restrict__ T0,
    short* __restrict__ T1, short* __restrict__ T2, short* __restrict__ T3) {
  const int t = threadIdx.x;
  if (blockIdx.y < 2) {
    const float* src = blockIdx.y ? y : x;
    short* dst = blockIdx.y ? yb : xb;
    size_t i = ((size_t)blockIdx.x * 256 + t) * 4;
    float4 v = *(const float4*)(src + i);
    bf16x4 o;
    o[0] = f2b(v.x); o[1] = f2b(v.y); o[2] = f2b(v.z); o[3] = f2b(v.w);
    *(bf16x4*)(dst + i) = o;
    return;
  }
  const int bx = blockIdx.x;
  if (bx >= 256) return;
  const int wj = bx >> 6, rem = bx & 63;
  const float* W = wj == 0 ? W0 : wj == 1 ? W1 : wj == 2 ? W2 : W3;
  short* T = wj == 0 ? T0 : wj == 1 ? T1 : wj == 2 ? T2 : T3;
  __shared__ float tile[64][65];
  const int k0 = (rem >> 3) * 64, n0 = (rem & 7) * 64;
#pragma unroll
  for (int i = 0; i < 4; ++i) {
    int r = (t >> 4) + i * 16;
    int c = (t & 15) * 4;
    float4 v = *(const float4*)&W[(size_t)(k0 + r) * ND + n0 + c];
    tile[r][c] = v.x; tile[r][c + 1] = v.y;
    tile[r][c + 2] = v.z; tile[r][c + 3] = v.w;
  }
  __syncthreads();
#pragma unroll
  for (int i = 0; i < 4; ++i) {
    int n = (t >> 4) + i * 16;
    int kc = (t & 15) * 4;
    bf16x4 o;
#pragma unroll
    for (int j = 0; j < 4; ++j) o[j] = f2b(tile[kc + j][n]);
    *(bf16x4*)&T[(size_t)(n0 + n) * ND + k0 + kc] = o;
  }
}

// ---------------------------------------------------------------------------
// QKV GEMM: 128x128 tile, 4 waves each 64x64 (acc 4x4), BK=64, single-buffer
// DMA staging (m97 2-barrier), XOR-swizzled LDS (pitch 64, chunk ^= row&7).
// mode 1: bf16 row-major out; 2: bf16 V^T out via LDS-transposed coalesced
// epilogue.  Tile ids (bx, by) are passed in (XCD-remapped by caller).
// ---------------------------------------------------------------------------
__device__ __forceinline__ void gemm128(const short* __restrict__ A,
                                        const short* __restrict__ Bt,
                                        short* __restrict__ Cout, int mode,
                                        float alpha, int bx, int by) {
  __shared__ short As[128 * 64];
  __shared__ short Bs[128 * 64];
  __shared__ short Tb[64 * 128];  // mode-2 transpose staging [c][r], 16 KB
  const int t = threadIdx.x;
  const int wave = t >> 6, lane = t & 63;
  const int m = lane & 15, quad = lane >> 4;
  const int m0 = by * 128, n0 = bx * 128;
  const int mh = (wave >> 1) * 64, nh = (wave & 1) * 64;
  const int r8 = lane >> 3;        // 0..7: row within wave's staging band
  const int c8 = (lane & 7) ^ r8;  // swizzled global chunk for this lane
  const int mx7 = m & 7;           // fragment-read swizzle key
  f32x4 acc[4][4];
#pragma unroll
  for (int i = 0; i < 4; ++i)
#pragma unroll
    for (int j = 0; j < 4; ++j) acc[i][j] = (f32x4){0.f, 0.f, 0.f, 0.f};

  for (int k0 = 0; k0 < ND; k0 += 64) {
    __syncthreads();  // prior iteration's fragment readers done
#pragma unroll
    for (int i = 0; i < 4; ++i) {
      int row = i * 32 + wave * 8 + r8;
      dma16(A + (size_t)(m0 + row) * ND + k0 + c8 * 8,
            As + (i * 256 + wave * 64) * 8);
      dma16(Bt + (size_t)(n0 + row) * ND + k0 + c8 * 8,
            Bs + (i * 256 + wave * 64) * 8);
    }
    __syncthreads();  // drains vmcnt: all DMA visible
    bf16x8 af[4][2], bf[4][2];
#pragma unroll
    for (int mt = 0; mt < 4; ++mt)
#pragma unroll
      for (int kc = 0; kc < 2; ++kc)
        af[mt][kc] = *(const bf16x8*)(As + (mh + mt * 16 + m) * 64 +
                                      ((kc * 4 + quad) ^ mx7) * 8);
#pragma unroll
    for (int nt = 0; nt < 4; ++nt)
#pragma unroll
      for (int kc = 0; kc < 2; ++kc)
        bf[nt][kc] = *(const bf16x8*)(Bs + (nh + nt * 16 + m) * 64 +
                                      ((kc * 4 + quad) ^ mx7) * 8);
#pragma unroll
    for (int mt = 0; mt < 4; ++mt)
#pragma unroll
      for (int nt = 0; nt < 4; ++nt)
#pragma unroll
        for (int kc = 0; kc < 2; ++kc)
          acc[mt][nt] = __builtin_amdgcn_mfma_f32_16x16x32_bf16(
              af[mt][kc], bf[nt][kc], acc[mt][nt], 0, 0, 0);
  }
  if (mode == 2) {
    // V^T epilogue: two 64-col passes through Tb[c][r], then each thread
    // writes 64 B of s-contiguous V^T (256 B contiguous per channel row).
    const int h0 = n0 >> 6;                        // n0 is 128-aligned
    const int b_ = m0 >> 11, s0g = m0 & (NS - 1);  // 128-row tile: one b
#pragma unroll
    for (int p = 0; p < 2; ++p) {
      __syncthreads();  // Tb free (p0: main loop done; p1: p0 readers done)
      if ((wave & 1) == p) {
        // wave's cols nh + nt*16 + m, nh == p*64 -> local c = nt*16 + m
#pragma unroll
        for (int mt = 0; mt < 4; ++mt)
#pragma unroll
          for (int nt = 0; nt < 4; ++nt)
#pragma unroll
            for (int r = 0; r < 4; ++r)
              Tb[(nt * 16 + m) * 128 + mh + mt * 16 + quad * 4 + r] =
                  f2b(acc[mt][nt][r] * alpha);
      }
      __syncthreads();
      {
        int c = t >> 2, sc = (t & 3) * 32;  // c: 0..63, sc: 0/32/64/96
        int gcol = p * 64 + c;
        int h_ = h0 + (gcol >> 6), d_ = gcol & (DEP - 1);
        short* dst =
            Cout + (size_t)((b_ * NH + h_) * DEP + d_) * NS + s0g + sc;
        const short* src = Tb + c * 128 + sc;
#pragma unroll
        for (int i = 0; i < 4; ++i)
          *(bf16x8*)(dst + i * 8) = *(const bf16x8*)(src + i * 8);
      }
    }
  } else {
#pragma unroll
    for (int mt = 0; mt < 4; ++mt)
#pragma unroll
      for (int nt = 0; nt < 4; ++nt)
#pragma unroll
        for (int r = 0; r < 4; ++r) {
          int row = m0 + mh + mt * 16 + quad * 4 + r;
          int col = n0 + nh + nt * 16 + m;
          Cout[(size_t)row * ND + col] = f2b(acc[mt][nt][r] * alpha);
        }
  }
}

// XCD-aware remap (T1): hardware block D lands on XCD D%8; remap so the 4
// blocks sharing one A-row-panel (consecutive work ids) share an XCD.
// D = xcd + 8*sl, sl in [0,96); w = (xcd*24 + (sl>>2))*4 + (sl&3).
// Bijective on [0,768); panel-sharers have D-stride 8 -> same XCD.
__global__ __launch_bounds__(256) void qkv_gemm(
    const short* __restrict__ xb, const short* __restrict__ yb,
    const short* __restrict__ Wqt, const short* __restrict__ Wkt,
    const short* __restrict__ Wvt, short* __restrict__ Qb,
    short* __restrict__ Kb, short* __restrict__ Vtb) {
  const int D = blockIdx.z * 256 + blockIdx.y * 4 + blockIdx.x;
  const int xcd = D & 7, sl = D >> 3;
  const int w = (xcd * 24 + (sl >> 2)) * 4 + (sl & 3);
  const int wx = w & 3, wy = (w >> 2) & 63, wz = w >> 8;
  if (wz == 0)
    gemm128(xb, Wqt, Qb, 1, QSCALE, wx, wy);  // scale + log2e folded into Q
  else if (wz == 1)
    gemm128(yb, Wkt, Kb, 1, 1.0f, wx, wy);
  else
    gemm128(yb, Wvt, Vtb, 2, 1.0f, wx, wy);
}

// ---------------------------------------------------------------------------
// Output GEMM: 128x64 tile, BK=64, double-buffered DMA, swizzled LDS,
// fp32 row-major out.  Grid 512 = 2 blocks/CU.  XCD-aware remap: the 8
// blocks sharing one A-row-panel land on one XCD (D=xcd+8*sl, sl in [0,64);
// w = (xcd*8 + (sl>>3))*8 + (sl&7); bijective on [0,512)).
// ---------------------------------------------------------------------------
__global__ __launch_bounds__(256) void out_gemm(const short* __restrict__ A,
                                                const short* __restrict__ Bt,
                                                float* __restrict__ Cout) {
  __shared__ short As[2][128 * 64];
  __shared__ short Bs[2][64 * 64];
  const int t = threadIdx.x;
  const int wave = t >> 6, lane = t & 63;
  const int m = lane & 15, quad = lane >> 4;
  const int D = blockIdx.y * 8 + blockIdx.x;
  const int xcd = D & 7, sl = D >> 3;
  const int w = (xcd * 8 + (sl >> 3)) * 8 + (sl & 7);
  const int m0 = (w >> 3) * 128, n0 = (w & 7) * 64;
  const int mh = (wave >> 1) * 64, nh = (wave & 1) * 32;
  const int r8 = lane >> 3;
  const int c8 = (lane & 7) ^ r8;
  const int mx7 = m & 7;
  f32x4 acc[4][2];
#pragma unroll
  for (int i = 0; i < 4; ++i)
#pragma unroll
    for (int j = 0; j < 2; ++j) acc[i][j] = (f32x4){0.f, 0.f, 0.f, 0.f};

#pragma unroll
  for (int i = 0; i < 4; ++i)
    dma16(A + (size_t)(m0 + i * 32 + wave * 8 + r8) * ND + c8 * 8,
          As[0] + (i * 256 + wave * 64) * 8);
#pragma unroll
  for (int i = 0; i < 2; ++i)
    dma16(Bt + (size_t)(n0 + i * 32 + wave * 8 + r8) * ND + c8 * 8,
          Bs[0] + (i * 256 + wave * 64) * 8);

  int buf = 0;
  for (int k0 = 0; k0 < ND; k0 += 64, buf ^= 1) {
    __syncthreads();
    if (k0 + 64 < ND) {
#pragma unroll
      for (int i = 0; i < 4; ++i)
        dma16(A + (size_t)(m0 + i * 32 + wave * 8 + r8) * ND + k0 + 64 + c8 * 8,
              As[buf ^ 1] + (i * 256 + wave * 64) * 8);
#pragma unroll
      for (int i = 0; i < 2; ++i)
        dma16(Bt + (size_t)(n0 + i * 32 + wave * 8 + r8) * ND + k0 + 64 +
                  c8 * 8,
              Bs[buf ^ 1] + (i * 256 + wave * 64) * 8);
    }
    bf16x8 af[4][2], bf[2][2];
#pragma unroll
    for (int mt = 0; mt < 4; ++mt)
#pragma unroll
      for (int kc = 0; kc < 2; ++kc)
        af[mt][kc] = *(const bf16x8*)(As[buf] + (mh + mt * 16 + m) * 64 +
                                      ((kc * 4 + quad) ^ mx7) * 8);
#pragma unroll
    for (int nt = 0; nt < 2; ++nt)
#pragma unroll
      for (int kc = 0; kc < 2; ++kc)
        bf[nt][kc] = *(const bf16x8*)(Bs[buf] + (nh + nt * 16 + m) * 64 +
                                      ((kc * 4 + quad) ^ mx7) * 8);
#pragma unroll
    for (int mt = 0; mt < 4; ++mt)
#pragma unroll
      for (int nt = 0; nt < 2; ++nt)
#pragma unroll
        for (int kc = 0; kc < 2; ++kc)
          acc[mt][nt] = __builtin_amdgcn_mfma_f32_16x16x32_bf16(
              af[mt][kc], bf[nt][kc], acc[mt][nt], 0, 0, 0);
  }
#pragma unroll
  for (int mt = 0; mt < 4; ++mt)
#pragma unroll
    for (int nt = 0; nt < 2; ++nt)
#pragma unroll
      for (int r = 0; r < 4; ++r) {
        int row = m0 + mh + mt * 16 + quad * 4 + r;
        int col = n0 + nh + nt * 16 + m;
        Cout[(size_t)row * ND + col] = acc[mt][nt][r];
      }
}

// ---------------------------------------------------------------------------
// Flash attention (r8 body + r11 XCD remap), S^T formulation, 32x32x16 MFMA,
// in-register softmax, in-block kv-split x2, single-buffered K/V (m97
// 2-barrier), 32.5 KB LDS.  XCD remap: all 16 q-blocks of one bh share an
// XCD (K/V working set 2 MB <= 4 MB L2; FETCH 70 -> 12 MB verified r11).
// Max-free softmax partials combine exactly in LDS: O=(O0+O1)/(l0+l1).
// Issue-bound at ~62% (MFMA 25% + VALU/trans ~42%); register cap (64 VGPR
// + 64 AGPR) locks TLP at 16 waves/CU -> ~52 us structural floor.
// ---------------------------------------------------------------------------
__global__ __launch_bounds__(512, 4) void attn_mfma(
    const short* __restrict__ Qb, const short* __restrict__ Kb,
    const short* __restrict__ Vtb, short* __restrict__ Ob) {
  __shared__ short KVs[2][2][64 * 64];  // [K=0/V=1][zh][kv/d tile], 32 KB
  __shared__ float lxs[128];            // cross-half l exchange
  const int t = threadIdx.x;
  const int wave = t >> 6, lane = t & 63;
  const int zh = wave >> 2, wl = wave & 3;  // kv-half, q-subtile
  const int l31 = lane & 31, hi = lane >> 5;
  const int sw = lane & 7;  // fragment-read swizzle key (row&7 == lane&7)
  // XCD-aware remap: L[2:0]=xcd, L[6:3]=q-tile, L[8:7]=bh-within-XCD.
  const int L = blockIdx.y * 16 + blockIdx.x;
  const int bh = (L & 7) * 4 + (L >> 7);
  const int qx = (L >> 3) & 15;
  const int b = bh >> 3, h = bh & 7;
  const int q0 = qx * 128 + wl * 32;
  const int kvb = zh * KVHALF;
  const size_t rowb = (size_t)b * NS;
  const short* Vtbase = Vtb + (size_t)(bh * DEP) * NS;
  const int r8 = lane >> 3;
  const int c8 = (lane & 7) ^ r8;
  short* Ksb = &KVs[0][zh][0];
  short* Vsb = &KVs[1][zh][0];

  // Q fragments (B-operand): col=q=l31, k(d) = dc*16 + hi*8 + j
  bf16x8 qf[4];
#pragma unroll
  for (int dc = 0; dc < 4; ++dc)
    qf[dc] = *(const bf16x8*)(Qb + (rowb + q0 + l31) * ND + h * DEP + dc * 16 +
                              hi * 8);

  // loop-invariant zero C-operand: avoids 32 v_mov per iteration (St init)
  f32x16 kzero;
#pragma unroll
  for (int i = 0; i < 16; ++i) kzero[i] = 0.f;

  float l_ = 0.0f;
  f32x16 Ot[2];
#pragma unroll
  for (int dt = 0; dt < 2; ++dt)
#pragma unroll
    for (int i = 0; i < 16; ++i) Ot[dt][i] = 0.f;

  for (int kv0 = 0; kv0 < KVHALF; kv0 += 64) {
    __syncthreads();  // prior iteration's fragment readers done
#pragma unroll
    for (int i = 0; i < 2; ++i) {
      int row = i * 32 + wl * 8 + r8;
      dma16(Kb + (rowb + kvb + kv0 + row) * ND + h * DEP + c8 * 8,
            Ksb + (i * 256 + wl * 64) * 8);
      dma16(Vtbase + (size_t)row * NS + kvb + kv0 + c8 * 8,
            Vsb + (i * 256 + wl * 64) * 8);
    }
    __syncthreads();  // drains vmcnt: K/V tiles visible

    // QK^T: St[kt] = S^T tile (kv = kt*32+row, q = col = l31)
    f32x16 St[2];
#pragma unroll
    for (int kt = 0; kt < 2; ++kt) {
      bf16x8 kf0 = *(const bf16x8*)(Ksb + (kt * 32 + l31) * 64 +
                                    (hi ^ sw) * 8);
      St[kt] = __builtin_amdgcn_mfma_f32_32x32x16_bf16(kf0, qf[0], kzero,
                                                       0, 0, 0);
#pragma unroll
      for (int dc = 1; dc < 4; ++dc) {
        bf16x8 kf = *(const bf16x8*)(Ksb + (kt * 32 + l31) * 64 +
                                     ((dc * 2 + hi) ^ sw) * 8);
        St[kt] = __builtin_amdgcn_mfma_f32_32x32x16_bf16(kf, qf[dc], St[kt],
                                                         0, 0, 0);
      }
    }

    // softmax (max-free, exp2) + in-register P^T -> B-fragment assembly.
    // St reg r (tile kt): kv = kt*32 + (r&3) + 8*(r>>2) + 4*hi.
    // B-frag slice s needs: elem j = P[kv0 + s*16 + hi*8 + j][q].
    bf16x8 pf[4];
    float rs = 0.f;
#pragma unroll
    for (int s = 0; s < 4; ++s) {
      const int kt = s >> 1, base = (s & 1) * 8;
      float E[8];
#pragma unroll
      for (int j = 0; j < 8; ++j) {
        E[j] = __builtin_amdgcn_exp2f(St[kt][base + j]);
      }
      rs += ((E[0] + E[1]) + (E[2] + E[3])) + ((E[4] + E[5]) + (E[6] + E[7]));
      unsigned A0 = pk2(E[0], E[1]), A1 = pk2(E[2], E[3]);
      unsigned A2 = pk2(E[4], E[5]), A3 = pk2(E[6], E[7]);
      // swap: out0 = [a.lo | b.lo], out1 = [a.hi | b.hi]
      auto r02 =
          __builtin_amdgcn_permlane32_swap((int)A0, (int)A2, false, false);
      auto r13 =
          __builtin_amdgcn_permlane32_swap((int)A1, (int)A3, false, false);
      union { bf16x8 v; int u[4]; } pu;
      pu.u[0] = r02[0]; pu.u[1] = r13[0]; pu.u[2] = r02[1]; pu.u[3] = r13[1];
      pf[s] = pu.v;
    }
    l_ += rs;

    // PV: Ot^T[dt] += V^T[d, kv-slice] * P^T[kv-slice, q]
#pragma unroll
    for (int dt = 0; dt < 2; ++dt)
#pragma unroll
      for (int s = 0; s < 4; ++s) {
        bf16x8 vf = *(const bf16x8*)(Vsb + (dt * 32 + l31) * 64 +
                                     ((s * 2 + hi) ^ sw) * 8);
        Ot[dt] = __builtin_amdgcn_mfma_f32_32x32x16_bf16(vf, pf[s], Ot[dt],
                                                         0, 0, 0);
      }
  }

  // per-wave denominator partial: lane l and l^32 hold complementary kv sets
  l_ += __shfl_xor(l_, 32, 64);

  // cross-half combine in LDS (aliased over dead K/V staging buffers).
  __syncthreads();  // all K/V fragment reads of the last tile complete
  float* Ox = (float*)KVs;  // [4][64][32] fp32 = 32 KB (spans KVs exactly)
  if (zh == 1) {
#pragma unroll
    for (int dt = 0; dt < 2; ++dt)
#pragma unroll
      for (int r = 0; r < 16; ++r) {
        int d = dt * 32 + (r & 3) + 8 * (r >> 2) + 4 * hi;
        Ox[(wl * 64 + d) * 32 + l31] = Ot[dt][r];
      }
    if (lane < 32) lxs[wl * 32 + l31] = l_;
  }
  __syncthreads();
  if (zh == 0) {
    float linv = 1.0f / (l_ + lxs[wl * 32 + l31]);
    size_t row = rowb + q0 + l31;
    // Ot reg r (tile dt): d = dt*32 + (r&3) + 8*(r>>2) + 4*hi -> 8B stores
#pragma unroll
    for (int dt = 0; dt < 2; ++dt)
#pragma unroll
      for (int g = 0; g < 4; ++g) {
        int d0 = dt * 32 + g * 8 + hi * 4;
        float o[4];
#pragma unroll
        for (int j = 0; j < 4; ++j)
          o[j] = Ot[dt][g * 4 + j] + Ox[(wl * 64 + d0 + j) * 32 + l31];
        uint2 pk;
        pk.x = pk2(o[0] * linv, o[1] * linv);
        pk.y = pk2(o[2] * linv, o[3] * linv);
        *(uint2*)(Ob + row * ND + h * DEP + d0) = pk;
      }
  }
}

// ---------------------------------------------------------------------------
extern "C" void kernel_launch(void* const* d_in, const int* in_sizes, int n_in,
                              void* d_out, int out_size, void* d_ws,
                              size_t ws_size, hipStream_t stream) {
  const float* x = (const float*)d_in[0];
  const float* y = (const float*)d_in[1];
  const float* Wq = (const float*)d_in[2];
  const float* Wk = (const float*)d_in[3];
  const float* Wv = (const float*)d_in[4];
  const float* Wo = (const float*)d_in[5];
  float* out = (float*)d_out;

  const size_t mat = (size_t)NB * NS * ND;
  const size_t wsz = (size_t)ND * ND;
  short* xb = (short*)d_ws;
  short* yb = xb + mat;
  short* Wqt = yb + mat;
  short* Wkt = Wqt + wsz;
  short* Wvt = Wkt + wsz;
  short* Wot = Wvt + wsz;
  short* Qb = Wot + wsz;
  short* Kb = Qb + mat;
  short* Vtb = Kb + mat;
  short* attnb = xb;  // reuse: xb dead after QKV GEMM

  prep<<<dim3(mat / 1024, 3), 256, 0, stream>>>(x, y, Wq, Wk, Wv, Wo, xb, yb,
                                                Wqt, Wkt, Wvt, Wot);
  qkv_gemm<<<dim3(ND / 128, (NB * NS) / 128, 3), 256, 0, stream>>>(
      xb, yb, Wqt, Wkt, Wvt, Qb, Kb, Vtb);
  attn_mfma<<<dim3(NS / 128, NB * NH), 512, 0, stream>>>(Qb, Kb, Vtb, attnb);
  out_gemm<<<dim3(ND / 64, (NB * NS) / 128), 256, 0, stream>>>(attnb, Wot,
                                                               out);
}

// Round 13
// 169.201 us; speedup vs baseline: 1.1400x; 1.0147x over previous
//
#include <hip/hip_runtime.h>
#include <hip/hip_bf16.h>
#include <math.h>
#include <stdint.h>

#define NB 4
#define NS 2048
#define ND 512
#define NH 8
#define DEP 64
#define KVHALF (NS / 2)

typedef __attribute__((ext_vector_type(8))) short bf16x8;
typedef __attribute__((ext_vector_type(4))) short bf16x4;
typedef __attribute__((ext_vector_type(4))) float f32x4;
typedef __attribute__((ext_vector_type(16))) float f32x16;

#define QSCALE 0.18033688011112042f  // DEPTH^-0.5 * log2(e): softmax in exp2

__device__ __forceinline__ short f2b(float f) {
  unsigned u = __float_as_uint(f);
  u += 0x7FFF + ((u >> 16) & 1);  // RNE
  return (short)(u >> 16);
}
__device__ __forceinline__ unsigned pk2(float a, float b) {
  union { __hip_bfloat162 h; unsigned u; } c;
  c.h = __float22bfloat162_rn(float2{a, b});
  return c.u;
}
// async 16B global->LDS DMA; LDS dest is wave-uniform base + lane*16
__device__ __forceinline__ void dma16(const void* g, void* l) {
  __builtin_amdgcn_global_load_lds(
      (const __attribute__((address_space(1))) void*)g,
      (__attribute__((address_space(3))) void*)l, 16, 0, 0);
}

// ---------------------------------------------------------------------------
// prep: one launch does BOTH input casts and all 4 weight transposes.
// grid (4096, 3): y=0 cast x, y=1 cast y, y=2 (x<256) transpose W0..W3.
// ---------------------------------------------------------------------------
__global__ __launch_bounds__(256) void prep(
    const float* __restrict__ x, const float* __restrict__ y,
    const float* __restrict__ W0, const float* __restrict__ W1,
    const float* __restrict__ W2, const float* __restrict__ W3,
    short* __restrict__ xb, short* __restrict__ yb, short* __restrict__ T0,
    short* __restrict__ T1, short* __restrict__ T2, short* __restrict__ T3) {
  const int t = threadIdx.x;
  if (blockIdx.y < 2) {
    const float* src = blockIdx.y ? y : x;
    short* dst = blockIdx.y ? yb : xb;
    size_t i = ((size_t)blockIdx.x * 256 + t) * 4;
    float4 v = *(const float4*)(src + i);
    bf16x4 o;
    o[0] = f2b(v.x); o[1] = f2b(v.y); o[2] = f2b(v.z); o[3] = f2b(v.w);
    *(bf16x4*)(dst + i) = o;
    return;
  }
  const int bx = blockIdx.x;
  if (bx >= 256) return;
  const int wj = bx >> 6, rem = bx & 63;
  const float* W = wj == 0 ? W0 : wj == 1 ? W1 : wj == 2 ? W2 : W3;
  short* T = wj == 0 ? T0 : wj == 1 ? T1 : wj == 2 ? T2 : T3;
  __shared__ float tile[64][65];
  const int k0 = (rem >> 3) * 64, n0 = (rem & 7) * 64;
#pragma unroll
  for (int i = 0; i < 4; ++i) {
    int r = (t >> 4) + i * 16;
    int c = (t & 15) * 4;
    float4 v = *(const float4*)&W[(size_t)(k0 + r) * ND + n0 + c];
    tile[r][c] = v.x; tile[r][c + 1] = v.y;
    tile[r][c + 2] = v.z; tile[r][c + 3] = v.w;
  }
  __syncthreads();
#pragma unroll
  for (int i = 0; i < 4; ++i) {
    int n = (t >> 4) + i * 16;
    int kc = (t & 15) * 4;
    bf16x4 o;
#pragma unroll
    for (int j = 0; j < 4; ++j) o[j] = f2b(tile[kc + j][n]);
    *(bf16x4*)&T[(size_t)(n0 + n) * ND + k0 + kc] = o;
  }
}

// ---------------------------------------------------------------------------
// QKV GEMM: 128x128 tile, 4 waves each 64x64 (acc 4x4), BK=64, single-buffer
// DMA staging (m97 2-barrier), XOR-swizzled LDS (pitch 64, chunk ^= row&7).
// mode 1: bf16 row-major out; 2: bf16 V^T out via LDS-transposed coalesced
// epilogue.  Tile ids (bx, by) are passed in (XCD-remapped by caller).
// ---------------------------------------------------------------------------
__device__ __forceinline__ void gemm128(const short* __restrict__ A,
                                        const short* __restrict__ Bt,
                                        short* __restrict__ Cout, int mode,
                                        float alpha, int bx, int by) {
  __shared__ short As[128 * 64];
  __shared__ short Bs[128 * 64];
  __shared__ short Tb[64 * 128];  // mode-2 transpose staging [c][r], 16 KB
  const int t = threadIdx.x;
  const int wave = t >> 6, lane = t & 63;
  const int m = lane & 15, quad = lane >> 4;
  const int m0 = by * 128, n0 = bx * 128;
  const int mh = (wave >> 1) * 64, nh = (wave & 1) * 64;
  const int r8 = lane >> 3;        // 0..7: row within wave's staging band
  const int c8 = (lane & 7) ^ r8;  // swizzled global chunk for this lane
  const int mx7 = m & 7;           // fragment-read swizzle key
  f32x4 acc[4][4];
#pragma unroll
  for (int i = 0; i < 4; ++i)
#pragma unroll
    for (int j = 0; j < 4; ++j) acc[i][j] = (f32x4){0.f, 0.f, 0.f, 0.f};

  for (int k0 = 0; k0 < ND; k0 += 64) {
    __syncthreads();  // prior iteration's fragment readers done
#pragma unroll
    for (int i = 0; i < 4; ++i) {
      int row = i * 32 + wave * 8 + r8;
      dma16(A + (size_t)(m0 + row) * ND + k0 + c8 * 8,
            As + (i * 256 + wave * 64) * 8);
      dma16(Bt + (size_t)(n0 + row) * ND + k0 + c8 * 8,
            Bs + (i * 256 + wave * 64) * 8);
    }
    __syncthreads();  // drains vmcnt: all DMA visible
    bf16x8 af[4][2], bf[4][2];
#pragma unroll
    for (int mt = 0; mt < 4; ++mt)
#pragma unroll
      for (int kc = 0; kc < 2; ++kc)
        af[mt][kc] = *(const bf16x8*)(As + (mh + mt * 16 + m) * 64 +
                                      ((kc * 4 + quad) ^ mx7) * 8);
#pragma unroll
    for (int nt = 0; nt < 4; ++nt)
#pragma unroll
      for (int kc = 0; kc < 2; ++kc)
        bf[nt][kc] = *(const bf16x8*)(Bs + (nh + nt * 16 + m) * 64 +
                                      ((kc * 4 + quad) ^ mx7) * 8);
#pragma unroll
    for (int mt = 0; mt < 4; ++mt)
#pragma unroll
      for (int nt = 0; nt < 4; ++nt)
#pragma unroll
        for (int kc = 0; kc < 2; ++kc)
          acc[mt][nt] = __builtin_amdgcn_mfma_f32_16x16x32_bf16(
              af[mt][kc], bf[nt][kc], acc[mt][nt], 0, 0, 0);
  }
  if (mode == 2) {
    // V^T epilogue: two 64-col passes through Tb[c][r], then each thread
    // writes 64 B of s-contiguous V^T (256 B contiguous per channel row).
    const int h0 = n0 >> 6;                        // n0 is 128-aligned
    const int b_ = m0 >> 11, s0g = m0 & (NS - 1);  // 128-row tile: one b
#pragma unroll
    for (int p = 0; p < 2; ++p) {
      __syncthreads();  // Tb free (p0: main loop done; p1: p0 readers done)
      if ((wave & 1) == p) {
        // wave's cols nh + nt*16 + m, nh == p*64 -> local c = nt*16 + m
#pragma unroll
        for (int mt = 0; mt < 4; ++mt)
#pragma unroll
          for (int nt = 0; nt < 4; ++nt)
#pragma unroll
            for (int r = 0; r < 4; ++r)
              Tb[(nt * 16 + m) * 128 + mh + mt * 16 + quad * 4 + r] =
                  f2b(acc[mt][nt][r] * alpha);
      }
      __syncthreads();
      {
        int c = t >> 2, sc = (t & 3) * 32;  // c: 0..63, sc: 0/32/64/96
        int gcol = p * 64 + c;
        int h_ = h0 + (gcol >> 6), d_ = gcol & (DEP - 1);
        short* dst =
            Cout + (size_t)((b_ * NH + h_) * DEP + d_) * NS + s0g + sc;
        const short* src = Tb + c * 128 + sc;
#pragma unroll
        for (int i = 0; i < 4; ++i)
          *(bf16x8*)(dst + i * 8) = *(const bf16x8*)(src + i * 8);
      }
    }
  } else {
#pragma unroll
    for (int mt = 0; mt < 4; ++mt)
#pragma unroll
      for (int nt = 0; nt < 4; ++nt)
#pragma unroll
        for (int r = 0; r < 4; ++r) {
          int row = m0 + mh + mt * 16 + quad * 4 + r;
          int col = n0 + nh + nt * 16 + m;
          Cout[(size_t)row * ND + col] = f2b(acc[mt][nt][r] * alpha);
        }
  }
}

// XCD-aware remap (T1), refined: K-blocks (wz=1) and V-blocks (wz=2) with
// the same row-panel BOTH read yb[wy] -- pair them on one XCD.  Per XCD:
// 8 xb-panels x 4 Q-blocks + 8 yb-panels x 8 K/V-blocks = 2 MB working set
// (<= 4 MB L2).  D = xcd + 8*sl, sl in [0,96); bijective on [0,768).
__global__ __launch_bounds__(256) void qkv_gemm(
    const short* __restrict__ xb, const short* __restrict__ yb,
    const short* __restrict__ Wqt, const short* __restrict__ Wkt,
    const short* __restrict__ Wvt, short* __restrict__ Qb,
    short* __restrict__ Kb, short* __restrict__ Vtb) {
  const int D = blockIdx.z * 256 + blockIdx.y * 4 + blockIdx.x;
  const int xcd = D & 7, sl = D >> 3;  // sl in [0,96)
  int wx, wy, wz;
  if (sl < 32) {  // Q: 4 blocks per xb-panel, panels xcd*8 .. xcd*8+7
    wz = 0;
    wy = xcd * 8 + (sl >> 2);
    wx = sl & 3;
  } else {  // K/V pair: 8 blocks per yb-panel (wz in {1,2} x wx in [0,4))
    int r = sl - 32;  // [0,64)
    wy = xcd * 8 + (r >> 3);
    wz = 1 + ((r >> 2) & 1);
    wx = r & 3;
  }
  if (wz == 0)
    gemm128(xb, Wqt, Qb, 1, QSCALE, wx, wy);  // scale + log2e folded into Q
  else if (wz == 1)
    gemm128(yb, Wkt, Kb, 1, 1.0f, wx, wy);
  else
    gemm128(yb, Wvt, Vtb, 2, 1.0f, wx, wy);
}

// ---------------------------------------------------------------------------
// Output GEMM: 128x64 tile, BK=64, double-buffered DMA, swizzled LDS,
// fp32 row-major out.  Grid 512 = 2 blocks/CU.  XCD-aware remap: the 8
// blocks sharing one A-row-panel land on one XCD (D=xcd+8*sl, sl in [0,64);
// w = (xcd*8 + (sl>>3))*8 + (sl&7); bijective on [0,512)).
// ---------------------------------------------------------------------------
__global__ __launch_bounds__(256) void out_gemm(const short* __restrict__ A,
                                                const short* __restrict__ Bt,
                                                float* __restrict__ Cout) {
  __shared__ short As[2][128 * 64];
  __shared__ short Bs[2][64 * 64];
  const int t = threadIdx.x;
  const int wave = t >> 6, lane = t & 63;
  const int m = lane & 15, quad = lane >> 4;
  const int D = blockIdx.y * 8 + blockIdx.x;
  const int xcd = D & 7, sl = D >> 3;
  const int w = (xcd * 8 + (sl >> 3)) * 8 + (sl & 7);
  const int m0 = (w >> 3) * 128, n0 = (w & 7) * 64;
  const int mh = (wave >> 1) * 64, nh = (wave & 1) * 32;
  const int r8 = lane >> 3;
  const int c8 = (lane & 7) ^ r8;
  const int mx7 = m & 7;
  f32x4 acc[4][2];
#pragma unroll
  for (int i = 0; i < 4; ++i)
#pragma unroll
    for (int j = 0; j < 2; ++j) acc[i][j] = (f32x4){0.f, 0.f, 0.f, 0.f};

#pragma unroll
  for (int i = 0; i < 4; ++i)
    dma16(A + (size_t)(m0 + i * 32 + wave * 8 + r8) * ND + c8 * 8,
          As[0] + (i * 256 + wave * 64) * 8);
#pragma unroll
  for (int i = 0; i < 2; ++i)
    dma16(Bt + (size_t)(n0 + i * 32 + wave * 8 + r8) * ND + c8 * 8,
          Bs[0] + (i * 256 + wave * 64) * 8);

  int buf = 0;
  for (int k0 = 0; k0 < ND; k0 += 64, buf ^= 1) {
    __syncthreads();
    if (k0 + 64 < ND) {
#pragma unroll
      for (int i = 0; i < 4; ++i)
        dma16(A + (size_t)(m0 + i * 32 + wave * 8 + r8) * ND + k0 + 64 + c8 * 8,
              As[buf ^ 1] + (i * 256 + wave * 64) * 8);
#pragma unroll
      for (int i = 0; i < 2; ++i)
        dma16(Bt + (size_t)(n0 + i * 32 + wave * 8 + r8) * ND + k0 + 64 +
                  c8 * 8,
              Bs[buf ^ 1] + (i * 256 + wave * 64) * 8);
    }
    bf16x8 af[4][2], bf[2][2];
#pragma unroll
    for (int mt = 0; mt < 4; ++mt)
#pragma unroll
      for (int kc = 0; kc < 2; ++kc)
        af[mt][kc] = *(const bf16x8*)(As[buf] + (mh + mt * 16 + m) * 64 +
                                      ((kc * 4 + quad) ^ mx7) * 8);
#pragma unroll
    for (int nt = 0; nt < 2; ++nt)
#pragma unroll
      for (int kc = 0; kc < 2; ++kc)
        bf[nt][kc] = *(const bf16x8*)(Bs[buf] + (nh + nt * 16 + m) * 64 +
                                      ((kc * 4 + quad) ^ mx7) * 8);
#pragma unroll
    for (int mt = 0; mt < 4; ++mt)
#pragma unroll
      for (int nt = 0; nt < 2; ++nt)
#pragma unroll
        for (int kc = 0; kc < 2; ++kc)
          acc[mt][nt] = __builtin_amdgcn_mfma_f32_16x16x32_bf16(
              af[mt][kc], bf[nt][kc], acc[mt][nt], 0, 0, 0);
  }
#pragma unroll
  for (int mt = 0; mt < 4; ++mt)
#pragma unroll
    for (int nt = 0; nt < 2; ++nt)
#pragma unroll
      for (int r = 0; r < 4; ++r) {
        int row = m0 + mh + mt * 16 + quad * 4 + r;
        int col = n0 + nh + nt * 16 + m;
        Cout[(size_t)row * ND + col] = acc[mt][nt][r];
      }
}

// ---------------------------------------------------------------------------
// Flash attention (r8 body + r11 XCD remap + T5 setprio on MFMA clusters).
// S^T formulation, 32x32x16 MFMA, in-register softmax, in-block kv-split
// x2, single-buffered K/V (m97 2-barrier), 32.5 KB LDS.  XCD remap: all 16
// q-blocks of one bh share an XCD (FETCH 70 -> 12 MB verified r11).
// Max-free softmax partials combine exactly in LDS: O=(O0+O1)/(l0+l1).
// Issue-bound at ~62% (MFMA 25% + VALU/trans ~42%); register cap (64 VGPR
// + 64 AGPR) locks TLP at 16 waves/CU -> ~52 us structural floor.
// ---------------------------------------------------------------------------
__global__ __launch_bounds__(512, 4) void attn_mfma(
    const short* __restrict__ Qb, const short* __restrict__ Kb,
    const short* __restrict__ Vtb, short* __restrict__ Ob) {
  __shared__ short KVs[2][2][64 * 64];  // [K=0/V=1][zh][kv/d tile], 32 KB
  __shared__ float lxs[128];            // cross-half l exchange
  const int t = threadIdx.x;
  const int wave = t >> 6, lane = t & 63;
  const int zh = wave >> 2, wl = wave & 3;  // kv-half, q-subtile
  const int l31 = lane & 31, hi = lane >> 5;
  const int sw = lane & 7;  // fragment-read swizzle key (row&7 == lane&7)
  // XCD-aware remap: L[2:0]=xcd, L[6:3]=q-tile, L[8:7]=bh-within-XCD.
  const int L = blockIdx.y * 16 + blockIdx.x;
  const int bh = (L & 7) * 4 + (L >> 7);
  const int qx = (L >> 3) & 15;
  const int b = bh >> 3, h = bh & 7;
  const int q0 = qx * 128 + wl * 32;
  const int kvb = zh * KVHALF;
  const size_t rowb = (size_t)b * NS;
  const short* Vtbase = Vtb + (size_t)(bh * DEP) * NS;
  const int r8 = lane >> 3;
  const int c8 = (lane & 7) ^ r8;
  short* Ksb = &KVs[0][zh][0];
  short* Vsb = &KVs[1][zh][0];

  // Q fragments (B-operand): col=q=l31, k(d) = dc*16 + hi*8 + j
  bf16x8 qf[4];
#pragma unroll
  for (int dc = 0; dc < 4; ++dc)
    qf[dc] = *(const bf16x8*)(Qb + (rowb + q0 + l31) * ND + h * DEP + dc * 16 +
                              hi * 8);

  // loop-invariant zero C-operand: avoids 32 v_mov per iteration (St init)
  f32x16 kzero;
#pragma unroll
  for (int i = 0; i < 16; ++i) kzero[i] = 0.f;

  float l_ = 0.0f;
  f32x16 Ot[2];
#pragma unroll
  for (int dt = 0; dt < 2; ++dt)
#pragma unroll
    for (int i = 0; i < 16; ++i) Ot[dt][i] = 0.f;

  for (int kv0 = 0; kv0 < KVHALF; kv0 += 64) {
    __syncthreads();  // prior iteration's fragment readers done
#pragma unroll
    for (int i = 0; i < 2; ++i) {
      int row = i * 32 + wl * 8 + r8;
      dma16(Kb + (rowb + kvb + kv0 + row) * ND + h * DEP + c8 * 8,
            Ksb + (i * 256 + wl * 64) * 8);
      dma16(Vtbase + (size_t)row * NS + kvb + kv0 + c8 * 8,
            Vsb + (i * 256 + wl * 64) * 8);
    }
    __syncthreads();  // drains vmcnt: K/V tiles visible

    // QK^T: St[kt] = S^T tile (kv = kt*32+row, q = col = l31)
    f32x16 St[2];
    __builtin_amdgcn_s_setprio(1);
#pragma unroll
    for (int kt = 0; kt < 2; ++kt) {
      bf16x8 kf0 = *(const bf16x8*)(Ksb + (kt * 32 + l31) * 64 +
                                    (hi ^ sw) * 8);
      St[kt] = __builtin_amdgcn_mfma_f32_32x32x16_bf16(kf0, qf[0], kzero,
                                                       0, 0, 0);
#pragma unroll
      for (int dc = 1; dc < 4; ++dc) {
        bf16x8 kf = *(const bf16x8*)(Ksb + (kt * 32 + l31) * 64 +
                                     ((dc * 2 + hi) ^ sw) * 8);
        St[kt] = __builtin_amdgcn_mfma_f32_32x32x16_bf16(kf, qf[dc], St[kt],
                                                         0, 0, 0);
      }
    }
    __builtin_amdgcn_s_setprio(0);

    // softmax (max-free, exp2) + in-register P^T -> B-fragment assembly.
    // St reg r (tile kt): kv = kt*32 + (r&3) + 8*(r>>2) + 4*hi.
    // B-frag slice s needs: elem j = P[kv0 + s*16 + hi*8 + j][q].
    bf16x8 pf[4];
    float rs = 0.f;
#pragma unroll
    for (int s = 0; s < 4; ++s) {
      const int kt = s >> 1, base = (s & 1) * 8;
      float E[8];
#pragma unroll
      for (int j = 0; j < 8; ++j) {
        E[j] = __builtin_amdgcn_exp2f(St[kt][base + j]);
      }
      rs += ((E[0] + E[1]) + (E[2] + E[3])) + ((E[4] + E[5]) + (E[6] + E[7]));
      unsigned A0 = pk2(E[0], E[1]), A1 = pk2(E[2], E[3]);
      unsigned A2 = pk2(E[4], E[5]), A3 = pk2(E[6], E[7]);
      // swap: out0 = [a.lo | b.lo], out1 = [a.hi | b.hi]
      auto r02 =
          __builtin_amdgcn_permlane32_swap((int)A0, (int)A2, false, false);
      auto r13 =
          __builtin_amdgcn_permlane32_swap((int)A1, (int)A3, false, false);
      union { bf16x8 v; int u[4]; } pu;
      pu.u[0] = r02[0]; pu.u[1] = r13[0]; pu.u[2] = r02[1]; pu.u[3] = r13[1];
      pf[s] = pu.v;
    }
    l_ += rs;

    // PV: Ot^T[dt] += V^T[d, kv-slice] * P^T[kv-slice, q]
    __builtin_amdgcn_s_setprio(1);
#pragma unroll
    for (int dt = 0; dt < 2; ++dt)
#pragma unroll
      for (int s = 0; s < 4; ++s) {
        bf16x8 vf = *(const bf16x8*)(Vsb + (dt * 32 + l31) * 64 +
                                     ((s * 2 + hi) ^ sw) * 8);
        Ot[dt] = __builtin_amdgcn_mfma_f32_32x32x16_bf16(vf, pf[s], Ot[dt],
                                                         0, 0, 0);
      }
    __builtin_amdgcn_s_setprio(0);
  }

  // per-wave denominator partial: lane l and l^32 hold complementary kv sets
  l_ += __shfl_xor(l_, 32, 64);

  // cross-half combine in LDS (aliased over dead K/V staging buffers).
  __syncthreads();  // all K/V fragment reads of the last tile complete
  float* Ox = (float*)KVs;  // [4][64][32] fp32 = 32 KB (spans KVs exactly)
  if (zh == 1) {
#pragma unroll
    for (int dt = 0; dt < 2; ++dt)
#pragma unroll
      for (int r = 0; r < 16; ++r) {
        int d = dt * 32 + (r & 3) + 8 * (r >> 2) + 4 * hi;
        Ox[(wl * 64 + d) * 32 + l31] = Ot[dt][r];
      }
    if (lane < 32) lxs[wl * 32 + l31] = l_;
  }
  __syncthreads();
  if (zh == 0) {
    float linv = 1.0f / (l_ + lxs[wl * 32 + l31]);
    size_t row = rowb + q0 + l31;
    // Ot reg r (tile dt): d = dt*32 + (r&3) + 8*(r>>2) + 4*hi -> 8B stores
#pragma unroll
    for (int dt = 0; dt < 2; ++dt)
#pragma unroll
      for (int g = 0; g < 4; ++g) {
        int d0 = dt * 32 + g * 8 + hi * 4;
        float o[4];
#pragma unroll
        for (int j = 0; j < 4; ++j)
          o[j] = Ot[dt][g * 4 + j] + Ox[(wl * 64 + d0 + j) * 32 + l31];
        uint2 pk;
        pk.x = pk2(o[0] * linv, o[1] * linv);
        pk.y = pk2(o[2] * linv, o[3] * linv);
        *(uint2*)(Ob + row * ND + h * DEP + d0) = pk;
      }
  }
}

// ---------------------------------------------------------------------------
extern "C" void kernel_launch(void* const* d_in, const int* in_sizes, int n_in,
                              void* d_out, int out_size, void* d_ws,
                              size_t ws_size, hipStream_t stream) {
  const float* x = (const float*)d_in[0];
  const float* y = (const float*)d_in[1];
  const float* Wq = (const float*)d_in[2];
  const float* Wk = (const float*)d_in[3];
  const float* Wv = (const float*)d_in[4];
  const float* Wo = (const float*)d_in[5];
  float* out = (float*)d_out;

  const size_t mat = (size_t)NB * NS * ND;
  const size_t wsz = (size_t)ND * ND;
  short* xb = (short*)d_ws;
  short* yb = xb + mat;
  short* Wqt = yb + mat;
  short* Wkt = Wqt + wsz;
  short* Wvt = Wkt + wsz;
  short* Wot = Wvt + wsz;
  short* Qb = Wot + wsz;
  short* Kb = Qb + mat;
  short* Vtb = Kb + mat;
  short* attnb = xb;  // reuse: xb dead after QKV GEMM

  prep<<<dim3(mat / 1024, 3), 256, 0, stream>>>(x, y, Wq, Wk, Wv, Wo, xb, yb,
                                                Wqt, Wkt, Wvt, Wot);
  qkv_gemm<<<dim3(ND / 128, (NB * NS) / 128, 3), 256, 0, stream>>>(
      xb, yb, Wqt, Wkt, Wvt, Qb, Kb, Vtb);
  attn_mfma<<<dim3(NS / 128, NB * NH), 512, 0, stream>>>(Qb, Kb, Vtb, attnb);
  out_gemm<<<dim3(ND / 64, (NB * NS) / 128), 256, 0, stream>>>(attnb, Wot,
                                                               out);
}

// Round 14
// 168.521 us; speedup vs baseline: 1.1446x; 1.0040x over previous
//
#include <hip/hip_runtime.h>
#include <hip/hip_bf16.h>
#include <math.h>
#include <stdint.h>

#define NB 4
#define NS 2048
#define ND 512
#define NH 8
#define DEP 64
#define KVHALF (NS / 2)

typedef __attribute__((ext_vector_type(8))) short bf16x8;
typedef __attribute__((ext_vector_type(4))) short bf16x4;
typedef __attribute__((ext_vector_type(4))) float f32x4;
typedef __attribute__((ext_vector_type(16))) float f32x16;

#define QSCALE 0.18033688011112042f  // DEPTH^-0.5 * log2(e): softmax in exp2

__device__ __forceinline__ short f2b(float f) {
  unsigned u = __float_as_uint(f);
  u += 0x7FFF + ((u >> 16) & 1);  // RNE
  return (short)(u >> 16);
}
__device__ __forceinline__ unsigned pk2(float a, float b) {
  union { __hip_bfloat162 h; unsigned u; } c;
  c.h = __float22bfloat162_rn(float2{a, b});
  return c.u;
}
// async 16B global->LDS DMA; LDS dest is wave-uniform base + lane*16
__device__ __forceinline__ void dma16(const void* g, void* l) {
  __builtin_amdgcn_global_load_lds(
      (const __attribute__((address_space(1))) void*)g,
      (__attribute__((address_space(3))) void*)l, 16, 0, 0);
}

// ---------------------------------------------------------------------------
// prep: one launch does BOTH input casts and all 4 weight transposes.
// grid (4096, 3): y=0 cast x, y=1 cast y, y=2 (x<256) transpose W0..W3.
// ---------------------------------------------------------------------------
__global__ __launch_bounds__(256) void prep(
    const float* __restrict__ x, const float* __restrict__ y,
    const float* __restrict__ W0, const float* __restrict__ W1,
    const float* __restrict__ W2, const float* __restrict__ W3,
    short* __restrict__ xb, short* __restrict__ yb, short* __restrict__ T0,
    short* __restrict__ T1, short* __restrict__ T2, short* __restrict__ T3) {
  const int t = threadIdx.x;
  if (blockIdx.y < 2) {
    const float* src = blockIdx.y ? y : x;
    short* dst = blockIdx.y ? yb : xb;
    size_t i = ((size_t)blockIdx.x * 256 + t) * 4;
    float4 v = *(const float4*)(src + i);
    bf16x4 o;
    o[0] = f2b(v.x); o[1] = f2b(v.y); o[2] = f2b(v.z); o[3] = f2b(v.w);
    *(bf16x4*)(dst + i) = o;
    return;
  }
  const int bx = blockIdx.x;
  if (bx >= 256) return;
  const int wj = bx >> 6, rem = bx & 63;
  const float* W = wj == 0 ? W0 : wj == 1 ? W1 : wj == 2 ? W2 : W3;
  short* T = wj == 0 ? T0 : wj == 1 ? T1 : wj == 2 ? T2 : T3;
  __shared__ float tile[64][65];
  const int k0 = (rem >> 3) * 64, n0 = (rem & 7) * 64;
#pragma unroll
  for (int i = 0; i < 4; ++i) {
    int r = (t >> 4) + i * 16;
    int c = (t & 15) * 4;
    float4 v = *(const float4*)&W[(size_t)(k0 + r) * ND + n0 + c];
    tile[r][c] = v.x; tile[r][c + 1] = v.y;
    tile[r][c + 2] = v.z; tile[r][c + 3] = v.w;
  }
  __syncthreads();
#pragma unroll
  for (int i = 0; i < 4; ++i) {
    int n = (t >> 4) + i * 16;
    int kc = (t & 15) * 4;
    bf16x4 o;
#pragma unroll
    for (int j = 0; j < 4; ++j) o[j] = f2b(tile[kc + j][n]);
    *(bf16x4*)&T[(size_t)(n0 + n) * ND + k0 + kc] = o;
  }
}

// ---------------------------------------------------------------------------
// QKV GEMM: 128x128 tile, 4 waves each 64x64 (acc 4x4), BK=64, single-buffer
// DMA staging (m97 2-barrier), XOR-swizzled LDS (pitch 64, chunk ^= row&7).
// mode 1: bf16 row-major out; 2: bf16 V^T out via LDS-transposed coalesced
// epilogue.  Tile ids (bx, by) are passed in (XCD-remapped by caller).
// ---------------------------------------------------------------------------
__device__ __forceinline__ void gemm128(const short* __restrict__ A,
                                        const short* __restrict__ Bt,
                                        short* __restrict__ Cout, int mode,
                                        float alpha, int bx, int by) {
  __shared__ short As[128 * 64];
  __shared__ short Bs[128 * 64];
  __shared__ short Tb[64 * 128];  // mode-2 transpose staging [c][r], 16 KB
  const int t = threadIdx.x;
  const int wave = t >> 6, lane = t & 63;
  const int m = lane & 15, quad = lane >> 4;
  const int m0 = by * 128, n0 = bx * 128;
  const int mh = (wave >> 1) * 64, nh = (wave & 1) * 64;
  const int r8 = lane >> 3;        // 0..7: row within wave's staging band
  const int c8 = (lane & 7) ^ r8;  // swizzled global chunk for this lane
  const int mx7 = m & 7;           // fragment-read swizzle key
  f32x4 acc[4][4];
#pragma unroll
  for (int i = 0; i < 4; ++i)
#pragma unroll
    for (int j = 0; j < 4; ++j) acc[i][j] = (f32x4){0.f, 0.f, 0.f, 0.f};

  for (int k0 = 0; k0 < ND; k0 += 64) {
    __syncthreads();  // prior iteration's fragment readers done
#pragma unroll
    for (int i = 0; i < 4; ++i) {
      int row = i * 32 + wave * 8 + r8;
      dma16(A + (size_t)(m0 + row) * ND + k0 + c8 * 8,
            As + (i * 256 + wave * 64) * 8);
      dma16(Bt + (size_t)(n0 + row) * ND + k0 + c8 * 8,
            Bs + (i * 256 + wave * 64) * 8);
    }
    __syncthreads();  // drains vmcnt: all DMA visible
    bf16x8 af[4][2], bf[4][2];
#pragma unroll
    for (int mt = 0; mt < 4; ++mt)
#pragma unroll
      for (int kc = 0; kc < 2; ++kc)
        af[mt][kc] = *(const bf16x8*)(As + (mh + mt * 16 + m) * 64 +
                                      ((kc * 4 + quad) ^ mx7) * 8);
#pragma unroll
    for (int nt = 0; nt < 4; ++nt)
#pragma unroll
      for (int kc = 0; kc < 2; ++kc)
        bf[nt][kc] = *(const bf16x8*)(Bs + (nh + nt * 16 + m) * 64 +
                                      ((kc * 4 + quad) ^ mx7) * 8);
#pragma unroll
    for (int mt = 0; mt < 4; ++mt)
#pragma unroll
      for (int nt = 0; nt < 4; ++nt)
#pragma unroll
        for (int kc = 0; kc < 2; ++kc)
          acc[mt][nt] = __builtin_amdgcn_mfma_f32_16x16x32_bf16(
              af[mt][kc], bf[nt][kc], acc[mt][nt], 0, 0, 0);
  }
  if (mode == 2) {
    // V^T epilogue: two 64-col passes through Tb[c][r], then each thread
    // writes 64 B of s-contiguous V^T (256 B contiguous per channel row).
    const int h0 = n0 >> 6;                        // n0 is 128-aligned
    const int b_ = m0 >> 11, s0g = m0 & (NS - 1);  // 128-row tile: one b
#pragma unroll
    for (int p = 0; p < 2; ++p) {
      __syncthreads();  // Tb free (p0: main loop done; p1: p0 readers done)
      if ((wave & 1) == p) {
        // wave's cols nh + nt*16 + m, nh == p*64 -> local c = nt*16 + m
#pragma unroll
        for (int mt = 0; mt < 4; ++mt)
#pragma unroll
          for (int nt = 0; nt < 4; ++nt)
#pragma unroll
            for (int r = 0; r < 4; ++r)
              Tb[(nt * 16 + m) * 128 + mh + mt * 16 + quad * 4 + r] =
                  f2b(acc[mt][nt][r] * alpha);
      }
      __syncthreads();
      {
        int c = t >> 2, sc = (t & 3) * 32;  // c: 0..63, sc: 0/32/64/96
        int gcol = p * 64 + c;
        int h_ = h0 + (gcol >> 6), d_ = gcol & (DEP - 1);
        short* dst =
            Cout + (size_t)((b_ * NH + h_) * DEP + d_) * NS + s0g + sc;
        const short* src = Tb + c * 128 + sc;
#pragma unroll
        for (int i = 0; i < 4; ++i)
          *(bf16x8*)(dst + i * 8) = *(const bf16x8*)(src + i * 8);
      }
    }
  } else {
#pragma unroll
    for (int mt = 0; mt < 4; ++mt)
#pragma unroll
      for (int nt = 0; nt < 4; ++nt)
#pragma unroll
        for (int r = 0; r < 4; ++r) {
          int row = m0 + mh + mt * 16 + quad * 4 + r;
          int col = n0 + nh + nt * 16 + m;
          Cout[(size_t)row * ND + col] = f2b(acc[mt][nt][r] * alpha);
        }
  }
}

// XCD-aware remap (T1), refined: K-blocks (wz=1) and V-blocks (wz=2) with
// the same row-panel BOTH read yb[wy] -- pair them on one XCD.  Per XCD:
// 8 xb-panels x 4 Q-blocks + 8 yb-panels x 8 K/V-blocks = 2 MB working set
// (<= 4 MB L2).  D = xcd + 8*sl, sl in [0,96); bijective on [0,768).
__global__ __launch_bounds__(256) void qkv_gemm(
    const short* __restrict__ xb, const short* __restrict__ yb,
    const short* __restrict__ Wqt, const short* __restrict__ Wkt,
    const short* __restrict__ Wvt, short* __restrict__ Qb,
    short* __restrict__ Kb, short* __restrict__ Vtb) {
  const int D = blockIdx.z * 256 + blockIdx.y * 4 + blockIdx.x;
  const int xcd = D & 7, sl = D >> 3;  // sl in [0,96)
  int wx, wy, wz;
  if (sl < 32) {  // Q: 4 blocks per xb-panel, panels xcd*8 .. xcd*8+7
    wz = 0;
    wy = xcd * 8 + (sl >> 2);
    wx = sl & 3;
  } else {  // K/V pair: 8 blocks per yb-panel (wz in {1,2} x wx in [0,4))
    int r = sl - 32;  // [0,64)
    wy = xcd * 8 + (r >> 3);
    wz = 1 + ((r >> 2) & 1);
    wx = r & 3;
  }
  if (wz == 0)
    gemm128(xb, Wqt, Qb, 1, QSCALE, wx, wy);  // scale + log2e folded into Q
  else if (wz == 1)
    gemm128(yb, Wkt, Kb, 1, 1.0f, wx, wy);
  else
    gemm128(yb, Wvt, Vtb, 2, 1.0f, wx, wy);
}

// ---------------------------------------------------------------------------
// Output GEMM: 128x64 tile, BK=64, double-buffered DMA, swizzled LDS,
// fp32 row-major out.  Grid 512 = 2 blocks/CU.  XCD-aware remap: the 8
// blocks sharing one A-row-panel land on one XCD (D=xcd+8*sl, sl in [0,64);
// w = (xcd*8 + (sl>>3))*8 + (sl&7); bijective on [0,512)).
// ---------------------------------------------------------------------------
__global__ __launch_bounds__(256) void out_gemm(const short* __restrict__ A,
                                                const short* __restrict__ Bt,
                                                float* __restrict__ Cout) {
  __shared__ short As[2][128 * 64];
  __shared__ short Bs[2][64 * 64];
  const int t = threadIdx.x;
  const int wave = t >> 6, lane = t & 63;
  const int m = lane & 15, quad = lane >> 4;
  const int D = blockIdx.y * 8 + blockIdx.x;
  const int xcd = D & 7, sl = D >> 3;
  const int w = (xcd * 8 + (sl >> 3)) * 8 + (sl & 7);
  const int m0 = (w >> 3) * 128, n0 = (w & 7) * 64;
  const int mh = (wave >> 1) * 64, nh = (wave & 1) * 32;
  const int r8 = lane >> 3;
  const int c8 = (lane & 7) ^ r8;
  const int mx7 = m & 7;
  f32x4 acc[4][2];
#pragma unroll
  for (int i = 0; i < 4; ++i)
#pragma unroll
    for (int j = 0; j < 2; ++j) acc[i][j] = (f32x4){0.f, 0.f, 0.f, 0.f};

#pragma unroll
  for (int i = 0; i < 4; ++i)
    dma16(A + (size_t)(m0 + i * 32 + wave * 8 + r8) * ND + c8 * 8,
          As[0] + (i * 256 + wave * 64) * 8);
#pragma unroll
  for (int i = 0; i < 2; ++i)
    dma16(Bt + (size_t)(n0 + i * 32 + wave * 8 + r8) * ND + c8 * 8,
          Bs[0] + (i * 256 + wave * 64) * 8);

  int buf = 0;
  for (int k0 = 0; k0 < ND; k0 += 64, buf ^= 1) {
    __syncthreads();
    if (k0 + 64 < ND) {
#pragma unroll
      for (int i = 0; i < 4; ++i)
        dma16(A + (size_t)(m0 + i * 32 + wave * 8 + r8) * ND + k0 + 64 + c8 * 8,
              As[buf ^ 1] + (i * 256 + wave * 64) * 8);
#pragma unroll
      for (int i = 0; i < 2; ++i)
        dma16(Bt + (size_t)(n0 + i * 32 + wave * 8 + r8) * ND + k0 + 64 +
                  c8 * 8,
              Bs[buf ^ 1] + (i * 256 + wave * 64) * 8);
    }
    bf16x8 af[4][2], bf[2][2];
#pragma unroll
    for (int mt = 0; mt < 4; ++mt)
#pragma unroll
      for (int kc = 0; kc < 2; ++kc)
        af[mt][kc] = *(const bf16x8*)(As[buf] + (mh + mt * 16 + m) * 64 +
                                      ((kc * 4 + quad) ^ mx7) * 8);
#pragma unroll
    for (int nt = 0; nt < 2; ++nt)
#pragma unroll
      for (int kc = 0; kc < 2; ++kc)
        bf[nt][kc] = *(const bf16x8*)(Bs[buf] + (nh + nt * 16 + m) * 64 +
                                      ((kc * 4 + quad) ^ mx7) * 8);
#pragma unroll
    for (int mt = 0; mt < 4; ++mt)
#pragma unroll
      for (int nt = 0; nt < 2; ++nt)
#pragma unroll
        for (int kc = 0; kc < 2; ++kc)
          acc[mt][nt] = __builtin_amdgcn_mfma_f32_16x16x32_bf16(
              af[mt][kc], bf[nt][kc], acc[mt][nt], 0, 0, 0);
  }
#pragma unroll
  for (int mt = 0; mt < 4; ++mt)
#pragma unroll
    for (int nt = 0; nt < 2; ++nt)
#pragma unroll
      for (int r = 0; r < 4; ++r) {
        int row = m0 + mh + mt * 16 + quad * 4 + r;
        int col = n0 + nh + nt * 16 + m;
        Cout[(size_t)row * ND + col] = acc[mt][nt][r];
      }
}

// ---------------------------------------------------------------------------
// Flash attention (r12 body: NO setprio -- r13 measured it at -1.1 us, the
// lockstep-wave structure makes priority boosts pure arbitration churn,
// matching m190's GEMM finding).  S^T formulation, 32x32x16 MFMA,
// in-register softmax, in-block kv-split x2, single-buffered K/V (m97
// 2-barrier), 32.5 KB LDS.  XCD remap: all 16 q-blocks of one bh share an
// XCD (FETCH 70 -> 12 MB verified r11).
// Max-free softmax partials combine exactly in LDS: O=(O0+O1)/(l0+l1).
// Issue-bound at ~62% (MFMA 25% + VALU/trans ~42%); register cap (64 VGPR
// + 64 AGPR) locks TLP at 16 waves/CU -> ~52 us structural floor.
// ---------------------------------------------------------------------------
__global__ __launch_bounds__(512, 4) void attn_mfma(
    const short* __restrict__ Qb, const short* __restrict__ Kb,
    const short* __restrict__ Vtb, short* __restrict__ Ob) {
  __shared__ short KVs[2][2][64 * 64];  // [K=0/V=1][zh][kv/d tile], 32 KB
  __shared__ float lxs[128];            // cross-half l exchange
  const int t = threadIdx.x;
  const int wave = t >> 6, lane = t & 63;
  const int zh = wave >> 2, wl = wave & 3;  // kv-half, q-subtile
  const int l31 = lane & 31, hi = lane >> 5;
  const int sw = lane & 7;  // fragment-read swizzle key (row&7 == lane&7)
  // XCD-aware remap: L[2:0]=xcd, L[6:3]=q-tile, L[8:7]=bh-within-XCD.
  const int L = blockIdx.y * 16 + blockIdx.x;
  const int bh = (L & 7) * 4 + (L >> 7);
  const int qx = (L >> 3) & 15;
  const int b = bh >> 3, h = bh & 7;
  const int q0 = qx * 128 + wl * 32;
  const int kvb = zh * KVHALF;
  const size_t rowb = (size_t)b * NS;
  const short* Vtbase = Vtb + (size_t)(bh * DEP) * NS;
  const int r8 = lane >> 3;
  const int c8 = (lane & 7) ^ r8;
  short* Ksb = &KVs[0][zh][0];
  short* Vsb = &KVs[1][zh][0];

  // Q fragments (B-operand): col=q=l31, k(d) = dc*16 + hi*8 + j
  bf16x8 qf[4];
#pragma unroll
  for (int dc = 0; dc < 4; ++dc)
    qf[dc] = *(const bf16x8*)(Qb + (rowb + q0 + l31) * ND + h * DEP + dc * 16 +
                              hi * 8);

  // loop-invariant zero C-operand: avoids 32 v_mov per iteration (St init)
  f32x16 kzero;
#pragma unroll
  for (int i = 0; i < 16; ++i) kzero[i] = 0.f;

  float l_ = 0.0f;
  f32x16 Ot[2];
#pragma unroll
  for (int dt = 0; dt < 2; ++dt)
#pragma unroll
    for (int i = 0; i < 16; ++i) Ot[dt][i] = 0.f;

  for (int kv0 = 0; kv0 < KVHALF; kv0 += 64) {
    __syncthreads();  // prior iteration's fragment readers done
#pragma unroll
    for (int i = 0; i < 2; ++i) {
      int row = i * 32 + wl * 8 + r8;
      dma16(Kb + (rowb + kvb + kv0 + row) * ND + h * DEP + c8 * 8,
            Ksb + (i * 256 + wl * 64) * 8);
      dma16(Vtbase + (size_t)row * NS + kvb + kv0 + c8 * 8,
            Vsb + (i * 256 + wl * 64) * 8);
    }
    __syncthreads();  // drains vmcnt: K/V tiles visible

    // QK^T: St[kt] = S^T tile (kv = kt*32+row, q = col = l31)
    f32x16 St[2];
#pragma unroll
    for (int kt = 0; kt < 2; ++kt) {
      bf16x8 kf0 = *(const bf16x8*)(Ksb + (kt * 32 + l31) * 64 +
                                    (hi ^ sw) * 8);
      St[kt] = __builtin_amdgcn_mfma_f32_32x32x16_bf16(kf0, qf[0], kzero,
                                                       0, 0, 0);
#pragma unroll
      for (int dc = 1; dc < 4; ++dc) {
        bf16x8 kf = *(const bf16x8*)(Ksb + (kt * 32 + l31) * 64 +
                                     ((dc * 2 + hi) ^ sw) * 8);
        St[kt] = __builtin_amdgcn_mfma_f32_32x32x16_bf16(kf, qf[dc], St[kt],
                                                         0, 0, 0);
      }
    }

    // softmax (max-free, exp2) + in-register P^T -> B-fragment assembly.
    // St reg r (tile kt): kv = kt*32 + (r&3) + 8*(r>>2) + 4*hi.
    // B-frag slice s needs: elem j = P[kv0 + s*16 + hi*8 + j][q].
    bf16x8 pf[4];
    float rs = 0.f;
#pragma unroll
    for (int s = 0; s < 4; ++s) {
      const int kt = s >> 1, base = (s & 1) * 8;
      float E[8];
#pragma unroll
      for (int j = 0; j < 8; ++j) {
        E[j] = __builtin_amdgcn_exp2f(St[kt][base + j]);
      }
      rs += ((E[0] + E[1]) + (E[2] + E[3])) + ((E[4] + E[5]) + (E[6] + E[7]));
      unsigned A0 = pk2(E[0], E[1]), A1 = pk2(E[2], E[3]);
      unsigned A2 = pk2(E[4], E[5]), A3 = pk2(E[6], E[7]);
      // swap: out0 = [a.lo | b.lo], out1 = [a.hi | b.hi]
      auto r02 =
          __builtin_amdgcn_permlane32_swap((int)A0, (int)A2, false, false);
      auto r13 =
          __builtin_amdgcn_permlane32_swap((int)A1, (int)A3, false, false);
      union { bf16x8 v; int u[4]; } pu;
      pu.u[0] = r02[0]; pu.u[1] = r13[0]; pu.u[2] = r02[1]; pu.u[3] = r13[1];
      pf[s] = pu.v;
    }
    l_ += rs;

    // PV: Ot^T[dt] += V^T[d, kv-slice] * P^T[kv-slice, q]
#pragma unroll
    for (int dt = 0; dt < 2; ++dt)
#pragma unroll
      for (int s = 0; s < 4; ++s) {
        bf16x8 vf = *(const bf16x8*)(Vsb + (dt * 32 + l31) * 64 +
                                     ((s * 2 + hi) ^ sw) * 8);
        Ot[dt] = __builtin_amdgcn_mfma_f32_32x32x16_bf16(vf, pf[s], Ot[dt],
                                                         0, 0, 0);
      }
  }

  // per-wave denominator partial: lane l and l^32 hold complementary kv sets
  l_ += __shfl_xor(l_, 32, 64);

  // cross-half combine in LDS (aliased over dead K/V staging buffers).
  __syncthreads();  // all K/V fragment reads of the last tile complete
  float* Ox = (float*)KVs;  // [4][64][32] fp32 = 32 KB (spans KVs exactly)
  if (zh == 1) {
#pragma unroll
    for (int dt = 0; dt < 2; ++dt)
#pragma unroll
      for (int r = 0; r < 16; ++r) {
        int d = dt * 32 + (r & 3) + 8 * (r >> 2) + 4 * hi;
        Ox[(wl * 64 + d) * 32 + l31] = Ot[dt][r];
      }
    if (lane < 32) lxs[wl * 32 + l31] = l_;
  }
  __syncthreads();
  if (zh == 0) {
    float linv = 1.0f / (l_ + lxs[wl * 32 + l31]);
    size_t row = rowb + q0 + l31;
    // Ot reg r (tile dt): d = dt*32 + (r&3) + 8*(r>>2) + 4*hi -> 8B stores
#pragma unroll
    for (int dt = 0; dt < 2; ++dt)
#pragma unroll
      for (int g = 0; g < 4; ++g) {
        int d0 = dt * 32 + g * 8 + hi * 4;
        float o[4];
#pragma unroll
        for (int j = 0; j < 4; ++j)
          o[j] = Ot[dt][g * 4 + j] + Ox[(wl * 64 + d0 + j) * 32 + l31];
        uint2 pk;
        pk.x = pk2(o[0] * linv, o[1] * linv);
        pk.y = pk2(o[2] * linv, o[3] * linv);
        *(uint2*)(Ob + row * ND + h * DEP + d0) = pk;
      }
  }
}

// ---------------------------------------------------------------------------
extern "C" void kernel_launch(void* const* d_in, const int* in_sizes, int n_in,
                              void* d_out, int out_size, void* d_ws,
                              size_t ws_size, hipStream_t stream) {
  const float* x = (const float*)d_in[0];
  const float* y = (const float*)d_in[1];
  const float* Wq = (const float*)d_in[2];
  const float* Wk = (const float*)d_in[3];
  const float* Wv = (const float*)d_in[4];
  const float* Wo = (const float*)d_in[5];
  float* out = (float*)d_out;

  const size_t mat = (size_t)NB * NS * ND;
  const size_t wsz = (size_t)ND * ND;
  short* xb = (short*)d_ws;
  short* yb = xb + mat;
  short* Wqt = yb + mat;
  short* Wkt = Wqt + wsz;
  short* Wvt = Wkt + wsz;
  short* Wot = Wvt + wsz;
  short* Qb = Wot + wsz;
  short* Kb = Qb + mat;
  short* Vtb = Kb + mat;
  short* attnb = xb;  // reuse: xb dead after QKV GEMM

  prep<<<dim3(mat / 1024, 3), 256, 0, stream>>>(x, y, Wq, Wk, Wv, Wo, xb, yb,
                                                Wqt, Wkt, Wvt, Wot);
  qkv_gemm<<<dim3(ND / 128, (NB * NS) / 128, 3), 256, 0, stream>>>(
      xb, yb, Wqt, Wkt, Wvt, Qb, Kb, Vtb);
  attn_mfma<<<dim3(NS / 128, NB * NH), 512, 0, stream>>>(Qb, Kb, Vtb, attnb);
  out_gemm<<<dim3(ND / 64, (NB * NS) / 128), 256, 0, stream>>>(attnb, Wot,
                                                               out);
}